// Round 8
// baseline (335.874 us; speedup 1.0000x reference)
//
#include <hip/hip_runtime.h>
#include <hip/hip_bf16.h>
#include <cstdint>
#include <cstddef>

#define TT 2048      // tokens (b*t)
#define DD 1024      // d
#define HH 2048      // h
#define NE 16        // experts
#define WM128 48     // max (expert, 128-row block) work items
#define WM64  80     // max (expert, 64-row block) work items
#define PSTR 528     // panel stride in u16: [32 k][16 n] + slack

typedef __bf16 bf16x8 __attribute__((ext_vector_type(8)));
typedef float f32x4 __attribute__((ext_vector_type(4)));
typedef __attribute__((address_space(3))) const unsigned short* lds_cu16;

__device__ __forceinline__ unsigned short f2bf(float f) {
  union { float f; unsigned u; } v; v.f = f;
  unsigned r = (v.u + 0x7FFFu + ((v.u >> 16) & 1u)) >> 16;  // RNE
  return (unsigned short)r;
}
__device__ __forceinline__ float bf2f(unsigned short s) {
  union { unsigned u; float f; } v; v.u = ((unsigned)s) << 16;
  return v.f;
}

__device__ __forceinline__ void gl_lds16(const void* g, void* l) {
  __builtin_amdgcn_global_load_lds(
      (const __attribute__((address_space(1))) unsigned int*)g,
      (__attribute__((address_space(3))) unsigned int*)l, 16, 0, 0);
}

// Two transpose-reads building a K-contiguous B-frag from a [32 k][16 n] panel.
__device__ __forceinline__ bf16x8 trfrag(const unsigned short* p) {
  lds_cu16 lp = (lds_cu16)p;
  unsigned long long a, b;
  asm volatile("ds_read_b64_tr_b16 %0, %1 offset:0"   : "=v"(a) : "v"(lp) : "memory");
  asm volatile("ds_read_b64_tr_b16 %0, %1 offset:128" : "=v"(b) : "v"(lp) : "memory");
  union { unsigned long long q[2]; bf16x8 v; } u;
  u.q[0] = a; u.q[1] = b;
  return u.v;
}

// ---------------- probe v3: DISCOVER tr-read semantics, validate end-to-end ----------------
// pm[0]=mode (0 fused / 3 fallback); pm[8+l]=p0 per lane; pm[80+j]=delta table.
__global__ void k_probe(int* __restrict__ pm) {
  __shared__ unsigned short lds[1024];
  const int l = threadIdx.x;          // 64 threads
  const int lr = l & 15, kg = l >> 4;
  for (int i = l; i < 1024; i += 64) lds[i] = 0xFFFF;
  __syncthreads();
  for (int i = l; i < 512; i += 64) lds[i] = (unsigned short)i;
  __syncthreads();
  // discovery: uniform base
  unsigned long long a, b;
  {
    lds_cu16 bp = (lds_cu16)&lds[0];
    asm volatile("ds_read_b64_tr_b16 %0, %1 offset:0"   : "=v"(a) : "v"(bp) : "memory");
    asm volatile("ds_read_b64_tr_b16 %0, %1 offset:128" : "=v"(b) : "v"(bp) : "memory");
  }
  asm volatile("s_waitcnt lgkmcnt(0)" ::: "memory");
  __builtin_amdgcn_sched_barrier(0);
  int pos[8];
  #pragma unroll
  for (int j = 0; j < 4; ++j) {
    pos[j]     = (int)((a >> (16 * j)) & 0xFFFF);
    pos[4 + j] = (int)((b >> (16 * j)) & 0xFFFF);
  }
  bool ok = true;
  int d[8];
  #pragma unroll
  for (int j = 0; j < 8; ++j) {
    ok = ok && (pos[j] < 512);
    d[j] = pos[j] - pos[0];
    int d0 = __shfl(d[j], 0);
    ok = ok && (d[j] == d0) && (d[j] >= 0) && (d[j] < 120);
  }
  const int p0 = pos[0];
  const int V = 128 * kg + lr - p0;
  ok = ok && (V >= 0) && (V < 512);
  ok = __all((int)ok);
  __syncthreads();
  // end-to-end: production write formula + production read
  for (int i = l; i < 1024; i += 64) lds[i] = 0xFFFF;
  __syncthreads();
  if (ok) {
    for (int i = l; i < 512; i += 64) {
      int k = i >> 4, n = i & 15;
      int p = 128 * (k >> 3) + n + d[k & 7];
      lds[p] = (unsigned short)(k * 64 + n);
    }
  }
  __syncthreads();
  unsigned long long a2, b2;
  {
    lds_cu16 bp = (lds_cu16)&lds[V >= 0 ? V : 0];
    asm volatile("ds_read_b64_tr_b16 %0, %1 offset:0"   : "=v"(a2) : "v"(bp) : "memory");
    asm volatile("ds_read_b64_tr_b16 %0, %1 offset:128" : "=v"(b2) : "v"(bp) : "memory");
  }
  asm volatile("s_waitcnt lgkmcnt(0)" ::: "memory");
  __builtin_amdgcn_sched_barrier(0);
  bool ok2 = ok;
  #pragma unroll
  for (int j = 0; j < 4; ++j) {
    ok2 = ok2 && ((int)((a2 >> (16 * j)) & 0xFFFF) == (8 * kg + j) * 64 + lr);
    ok2 = ok2 && ((int)((b2 >> (16 * j)) & 0xFFFF) == (8 * kg + 4 + j) * 64 + lr);
  }
  ok2 = __all((int)ok2);
  pm[8 + l] = p0;
  if (l == 0) {
    pm[0] = ok2 ? 0 : 3;
    #pragma unroll
    for (int j = 0; j < 8; ++j) pm[80 + j] = d[j];
  }
}

// ---------------- x fp32 -> bf16 ----------------
__global__ __launch_bounds__(256) void k_cvt_x(const float* __restrict__ x,
                                               unsigned short* __restrict__ xbf) {
  int i = blockIdx.x * 256 + threadIdx.x;
  const float4* p = reinterpret_cast<const float4*>(x) + (size_t)i * 2;
  float4 a = p[0], b = p[1];
  ushort4 o0 = { f2bf(a.x), f2bf(a.y), f2bf(a.z), f2bf(a.w) };
  ushort4 o1 = { f2bf(b.x), f2bf(b.y), f2bf(b.z), f2bf(b.w) };
  reinterpret_cast<ushort4*>(xbf)[(size_t)i * 2]     = o0;
  reinterpret_cast<ushort4*>(xbf)[(size_t)i * 2 + 1] = o1;
}

// ---------------- fallback transpose v2: u32-paired, swizzled, b128 reads ----------------
__global__ __launch_bounds__(256) void k_trans(const float* __restrict__ src0,
                                               const float* __restrict__ src1,
                                               unsigned short* __restrict__ dst0,
                                               unsigned short* __restrict__ dst1,
                                               int R, int C, const int* __restrict__ pm) {
  if (pm[0] != 3) return;
  __shared__ unsigned int tb[64][36];   // [c][rp swizzled], 9.2 KB
  const int e = blockIdx.z & 15;
  const int m = blockIdx.z >> 4;
  const float* src = m ? src1 : src0;
  unsigned short* dst = m ? dst1 : dst0;
  const int c0 = blockIdx.x * 64, r0 = blockIdx.y * 64;
  const float* s = src + (size_t)e * R * C;
  unsigned short* d = dst + (size_t)e * R * C;
  const int tid = threadIdx.x;
  const int cw = (tid & 15) * 4;
  #pragma unroll
  for (int p = 0; p < 2; ++p) {
    int r = p * 32 + (tid >> 4) * 2;
    int rp = p * 16 + (tid >> 4);
    float4 v0 = *reinterpret_cast<const float4*>(s + (size_t)(r0 + r) * C + c0 + cw);
    float4 v1 = *reinterpret_cast<const float4*>(s + (size_t)(r0 + r + 1) * C + c0 + cw);
    const float* f0 = reinterpret_cast<const float*>(&v0);
    const float* f1 = reinterpret_cast<const float*>(&v1);
    #pragma unroll
    for (int i = 0; i < 4; ++i) {
      int c = cw + i;
      unsigned u = (unsigned)f2bf(f0[i]) | ((unsigned)f2bf(f1[i]) << 16);
      tb[c][rp ^ (((c >> 2) & 7) << 2)] = u;   // u32 holds (r=2rp, r=2rp+1) at col c
    }
  }
  __syncthreads();
  #pragma unroll
  for (int q = 0; q < 2; ++q) {
    int c = q * 32 + (tid >> 3);
    int ss = tid & 7;
    int f = (c >> 2) & 7;
    uint4 o = *reinterpret_cast<const uint4*>(&tb[c][4 * (ss ^ f)]);  // r = 8ss..8ss+7
    *reinterpret_cast<uint4*>(d + (size_t)(c0 + c) * R + r0 + 8 * ss) = o;
  }
}

// ---------------- router + top-2 + bucketing ----------------
__global__ __launch_bounds__(256) void k_router(
    const float* __restrict__ x, const float* __restrict__ rw,
    const float* __restrict__ rb, int* __restrict__ cnt,
    int* __restrict__ list_tok, int* __restrict__ rec,
    float* __restrict__ wrec) {
  const int t = blockIdx.x;
  __shared__ float xs[DD];
  __shared__ float part[256];
  __shared__ float sc[NE];
  const float* xr = x + (size_t)t * DD;
  for (int i = threadIdx.x; i < DD; i += 256) xs[i] = xr[i];
  __syncthreads();
  const int e = threadIdx.x >> 4, j = threadIdx.x & 15;
  const float* w = rw + (size_t)e * DD;
  float s = 0.f;
  for (int i = j; i < DD; i += 16) s += xs[i] * w[i];
  part[threadIdx.x] = s;
  __syncthreads();
  if (threadIdx.x < NE) {
    float v = rb[threadIdx.x];
    #pragma unroll
    for (int q = 0; q < 16; ++q) v += part[threadIdx.x * 16 + q];
    sc[threadIdx.x] = v;
  }
  __syncthreads();
  if (threadIdx.x == 0) {
    int e1 = 0; float v1 = sc[0];
    #pragma unroll
    for (int q = 1; q < NE; ++q) { if (sc[q] > v1) { v1 = sc[q]; e1 = q; } }
    int e2 = -1; float v2 = -3.4e38f;
    #pragma unroll
    for (int q = 0; q < NE; ++q) {
      if (q != e1 && sc[q] > v2) { v2 = sc[q]; e2 = q; }
    }
    float ex = expf(v2 - v1);
    float w1 = 1.f / (1.f + ex);
    float w2 = ex / (1.f + ex);
    int p1 = atomicAdd(&cnt[e1], 1);
    int p2 = atomicAdd(&cnt[e2], 1);
    list_tok[e1 * TT + p1] = t;
    list_tok[e2 * TT + p2] = t;
    rec[t * 4 + 0] = e1; rec[t * 4 + 1] = p1;
    rec[t * 4 + 2] = e2; rec[t * 4 + 3] = p2;
    wrec[t * 2 + 0] = w1; wrec[t * 2 + 1] = w2;
  }
}

// ---------------- work-table builder ----------------
__global__ void k_sched(const int* __restrict__ cnt, int* __restrict__ work128,
                        int* __restrict__ work64, int* __restrict__ woff) {
  if (threadIdx.x == 0) {
    int o = 0, n1 = 0, n2 = 0;
    for (int e = 0; e < NE; ++e) {
      int ce = cnt[e];
      int a = (ce + 127) >> 7;
      for (int mb = 0; mb < a; ++mb) { work128[n1 * 2] = e; work128[n1 * 2 + 1] = mb; ++n1; }
      int b = (ce + 63) >> 6;
      for (int mb = 0; mb < b; ++mb) { work64[n2 * 2] = e; work64[n2 * 2 + 1] = mb; ++n2; }
      woff[e] = o; o += ce;
    }
    for (int q = n1; q < WM128; ++q) { work128[q * 2] = -1; work128[q * 2 + 1] = 0; }
    for (int q = n2; q < WM64; ++q)  { work64[q * 2] = -1;  work64[q * 2 + 1] = 0; }
  }
}

// ---------------- up GEMMs (mag,freq) + activation ----------------
__global__ __launch_bounds__(256, 3) void k_up(
    const unsigned short* __restrict__ xbf,
    const float* __restrict__ bmag, const float* __restrict__ bfreq,
    const unsigned short* __restrict__ wmT, const unsigned short* __restrict__ wfT,
    const float* __restrict__ bphase,
    const int* __restrict__ cnt, const int* __restrict__ list_tok,
    const int* __restrict__ work, const int* __restrict__ woff,
    const int* __restrict__ pm,
    unsigned short* __restrict__ hid) {
  const int e = work[blockIdx.x * 2 + 0];
  if (e < 0) return;
  const int mt = work[blockIdx.x * 2 + 1];
  const int nt = blockIdx.y;
  const int ce = cnt[e];
  const int off = woff[e];
  const int tmode = pm[0];
  __shared__ unsigned short As[2][128][32];
  __shared__ unsigned short Bst[2][2][4 * PSTR];
  __shared__ int toks[128];
  const int tid = threadIdx.x;
  if (tid < 128) {
    int r = mt * 128 + tid;
    toks[tid] = list_tok[e * TT + (r < ce ? r : ce - 1)];
  }
  __syncthreads();
  const int w = tid >> 6, l = tid & 63;
  size_t abase[2]; int aoff[2];
  #pragma unroll
  for (int p = 0; p < 2; ++p) {
    int row = p * 64 + w * 16 + (l >> 2);
    int g = (l & 3) ^ ((row >> 1) & 3);
    abase[p] = (size_t)toks[row] * DD + g * 8;
    aoff[p] = (p * 256 + w * 64 + l) * 8;
  }
  const int n0 = nt * 64;
  const int wm = (w >> 1) * 64, wn = (w & 1) * 32;
  const int lr = l & 15, kg = l >> 4;
  const f32x4 zero = {0.f, 0.f, 0.f, 0.f};
  f32x4 accM[4][2], accF[4][2];
  #pragma unroll
  for (int a = 0; a < 4; ++a)
    #pragma unroll
    for (int b = 0; b < 2; ++b) { accM[a][b] = zero; accF[a][b] = zero; }

  if (tmode < 3) {
    // ---------- fused: fp32 weights -> reg -> cvt -> panels (probe layout) -> tr-read ----------
    const float* srcM = bmag  + (size_t)e * DD * HH + n0;
    const float* srcF = bfreq + (size_t)e * DD * HH + n0;
    int bgl[2], bwr[2];
    #pragma unroll
    for (int s = 0; s < 2; ++s) {
      int idx = s * 256 + tid;
      int k = idx >> 4;
      bgl[s] = k * HH + (idx & 15) * 4;
      bwr[s] = ((idx >> 2) & 3) * PSTR + 128 * (k >> 3) + (idx & 3) * 4 + pm[80 + (k & 7)];
    }
    const int V = 128 * kg + lr - pm[8 + l];
    const int tb0 = ((w & 1) * 2) * PSTR + V;
    const int tb1 = tb0 + PSTR;
    float4 rm[2], rf[2];
    #pragma unroll
    for (int s = 0; s < 2; ++s) {
      rm[s] = *reinterpret_cast<const float4*>(srcM + bgl[s]);
      rf[s] = *reinterpret_cast<const float4*>(srcF + bgl[s]);
    }
    #pragma unroll
    for (int p = 0; p < 2; ++p) gl_lds16(xbf + abase[p], &As[0][0][0] + aoff[p]);
    #pragma unroll
    for (int s = 0; s < 2; ++s) {
      ushort4 om = { f2bf(rm[s].x), f2bf(rm[s].y), f2bf(rm[s].z), f2bf(rm[s].w) };
      ushort4 of = { f2bf(rf[s].x), f2bf(rf[s].y), f2bf(rf[s].z), f2bf(rf[s].w) };
      *reinterpret_cast<ushort4*>(&Bst[0][0][bwr[s]]) = om;
      *reinterpret_cast<ushort4*>(&Bst[0][1][bwr[s]]) = of;
    }
    __syncthreads();
    int buf = 0;
    for (int kt = 0; kt < DD / 32; ++kt) {
      const int nxt = kt + 1;
      const bool more = nxt < DD / 32;
      if (more) {
        const size_t g = (size_t)nxt * (32 * HH);
        #pragma unroll
        for (int s = 0; s < 2; ++s) {
          rm[s] = *reinterpret_cast<const float4*>(srcM + g + bgl[s]);
          rf[s] = *reinterpret_cast<const float4*>(srcF + g + bgl[s]);
        }
        #pragma unroll
        for (int p = 0; p < 2; ++p)
          gl_lds16(xbf + abase[p] + nxt * 32, &As[buf ^ 1][0][0] + aoff[p]);
      }
      bf16x8 av[4];
      #pragma unroll
      for (int fm = 0; fm < 4; ++fm) {
        int row = wm + fm * 16 + lr;
        int c = kg ^ ((row >> 1) & 3);
        av[fm] = *reinterpret_cast<const bf16x8*>(&As[buf][row][c * 8]);
      }
      bf16x8 bmv0 = trfrag(&Bst[buf][0][0] + tb0);
      bf16x8 bmv1 = trfrag(&Bst[buf][0][0] + tb1);
      bf16x8 bfv0 = trfrag(&Bst[buf][1][0] + tb0);
      bf16x8 bfv1 = trfrag(&Bst[buf][1][0] + tb1);
      asm volatile("s_waitcnt lgkmcnt(0)" ::: "memory");
      __builtin_amdgcn_sched_barrier(0);
      #pragma unroll
      for (int fm = 0; fm < 4; ++fm) {
        accM[fm][0] = __builtin_amdgcn_mfma_f32_16x16x32_bf16(av[fm], bmv0, accM[fm][0], 0, 0, 0);
        accM[fm][1] = __builtin_amdgcn_mfma_f32_16x16x32_bf16(av[fm], bmv1, accM[fm][1], 0, 0, 0);
        accF[fm][0] = __builtin_amdgcn_mfma_f32_16x16x32_bf16(av[fm], bfv0, accF[fm][0], 0, 0, 0);
        accF[fm][1] = __builtin_amdgcn_mfma_f32_16x16x32_bf16(av[fm], bfv1, accF[fm][1], 0, 0, 0);
      }
      if (more) {
        #pragma unroll
        for (int s = 0; s < 2; ++s) {
          ushort4 om = { f2bf(rm[s].x), f2bf(rm[s].y), f2bf(rm[s].z), f2bf(rm[s].w) };
          ushort4 of = { f2bf(rf[s].x), f2bf(rf[s].y), f2bf(rf[s].z), f2bf(rf[s].w) };
          *reinterpret_cast<ushort4*>(&Bst[buf ^ 1][0][bwr[s]]) = om;
          *reinterpret_cast<ushort4*>(&Bst[buf ^ 1][1][bwr[s]]) = of;
        }
      }
      __syncthreads();
      buf ^= 1;
    }
  } else {
    // ---------- fallback: pre-transposed bf16 weights via gl_lds ----------
    const int nrow = tid >> 2;
    const int gB = (tid & 3) ^ ((nrow >> 1) & 3);
    const size_t bbase = ((size_t)e * HH + n0 + nrow) * DD + gB * 8;
    const int boff = tid * 8;
    #pragma unroll
    for (int p = 0; p < 2; ++p) gl_lds16(xbf + abase[p], &As[0][0][0] + aoff[p]);
    gl_lds16(wmT + bbase, &Bst[0][0][0] + boff);
    gl_lds16(wfT + bbase, &Bst[0][1][0] + boff);
    __syncthreads();
    int buf = 0;
    for (int kt = 0; kt < DD / 32; ++kt) {
      const int nxt = kt + 1;
      if (nxt < DD / 32) {
        #pragma unroll
        for (int p = 0; p < 2; ++p)
          gl_lds16(xbf + abase[p] + nxt * 32, &As[buf ^ 1][0][0] + aoff[p]);
        gl_lds16(wmT + bbase + nxt * 32, &Bst[buf ^ 1][0][0] + boff);
        gl_lds16(wfT + bbase + nxt * 32, &Bst[buf ^ 1][1][0] + boff);
      }
      bf16x8 av[4], bmv[2], bfv[2];
      #pragma unroll
      for (int fm = 0; fm < 4; ++fm) {
        int row = wm + fm * 16 + lr;
        int c = kg ^ ((row >> 1) & 3);
        av[fm] = *reinterpret_cast<const bf16x8*>(&As[buf][row][c * 8]);
      }
      #pragma unroll
      for (int fn = 0; fn < 2; ++fn) {
        int row = wn + fn * 16 + lr;
        int c = kg ^ ((row >> 1) & 3);
        bmv[fn] = *reinterpret_cast<const bf16x8*>(&Bst[buf][0][row * 32 + c * 8]);
        bfv[fn] = *reinterpret_cast<const bf16x8*>(&Bst[buf][1][row * 32 + c * 8]);
      }
      #pragma unroll
      for (int fm = 0; fm < 4; ++fm)
        #pragma unroll
        for (int fn = 0; fn < 2; ++fn) {
          accM[fm][fn] = __builtin_amdgcn_mfma_f32_16x16x32_bf16(av[fm], bmv[fn], accM[fm][fn], 0, 0, 0);
          accF[fm][fn] = __builtin_amdgcn_mfma_f32_16x16x32_bf16(av[fm], bfv[fn], accF[fm][fn], 0, 0, 0);
        }
      __syncthreads();
      buf ^= 1;
    }
  }
  #pragma unroll
  for (int fn = 0; fn < 2; ++fn) {
    const int ng = n0 + wn + fn * 16 + lr;
    const float ph = bphase[e * HH + ng] + 0.1f;
    #pragma unroll
    for (int fm = 0; fm < 4; ++fm) {
      #pragma unroll
      for (int jj = 0; jj < 4; ++jj) {
        int m = mt * 128 + wm + fm * 16 + kg * 4 + jj;
        if (m < ce) {
          float mv = accM[fm][fn][jj];
          float fv = accF[fm][fn][jj];
          float exn = __expf(-fabsf(fv));
          float sp = fmaxf(fv, 0.f) + __logf(1.f + exn);   // stable softplus
          float t2 = __expf(2.f * mv);
          float th = 1.f - 2.f / (t2 + 1.f);               // tanh
          float hv = th * __cosf(sp + ph);
          hid[(size_t)(off + m) * HH + ng] = f2bf(hv);
        }
      }
    }
  }
}

// ---------------- down GEMM ----------------
__global__ __launch_bounds__(256, 4) void k_down(
    const unsigned short* __restrict__ hid,
    const float* __restrict__ bdown,
    const unsigned short* __restrict__ wdT,
    const int* __restrict__ cnt,
    const int* __restrict__ work, const int* __restrict__ woff,
    const int* __restrict__ pm,
    unsigned short* __restrict__ op) {
  const int e = work[blockIdx.x * 2 + 0];
  if (e < 0) return;
  const int mt = work[blockIdx.x * 2 + 1];
  const int nt = blockIdx.y;
  const int ce = cnt[e];
  const int off = woff[e];
  const int tmode = pm[0];
  __shared__ unsigned short As[2][64][32];
  __shared__ unsigned short Bst[2][4 * PSTR];
  const int tid = threadIdx.x;
  const int w = tid >> 6, l = tid & 63;
  const int row0 = tid >> 2;
  int gr = mt * 64 + row0; if (gr >= ce) gr = ce - 1;
  const size_t abase = (size_t)(off + gr) * HH + (size_t)(((tid & 3) ^ ((row0 >> 1) & 3)) * 8);
  const int aoff = tid * 8;
  const int n0 = nt * 64;
  const int wm = (w >> 1) * 32, wn = (w & 1) * 32;
  const int lr = l & 15, kg = l >> 4;
  const f32x4 zero = {0.f, 0.f, 0.f, 0.f};
  f32x4 acc[2][2];
  #pragma unroll
  for (int a = 0; a < 2; ++a)
    #pragma unroll
    for (int b = 0; b < 2; ++b) acc[a][b] = zero;

  if (tmode < 3) {
    const float* srcD = bdown + (size_t)e * HH * DD + n0;
    int bgl[2], bwr[2];
    #pragma unroll
    for (int s = 0; s < 2; ++s) {
      int idx = s * 256 + tid;
      int k = idx >> 4;
      bgl[s] = k * DD + (idx & 15) * 4;
      bwr[s] = ((idx >> 2) & 3) * PSTR + 128 * (k >> 3) + (idx & 3) * 4 + pm[80 + (k & 7)];
    }
    const int V = 128 * kg + lr - pm[8 + l];
    const int tb0 = ((w & 1) * 2) * PSTR + V;
    const int tb1 = tb0 + PSTR;
    float4 rd[2];
    #pragma unroll
    for (int s = 0; s < 2; ++s) rd[s] = *reinterpret_cast<const float4*>(srcD + bgl[s]);
    gl_lds16(hid + abase, &As[0][0][0] + aoff);
    #pragma unroll
    for (int s = 0; s < 2; ++s) {
      ushort4 o = { f2bf(rd[s].x), f2bf(rd[s].y), f2bf(rd[s].z), f2bf(rd[s].w) };
      *reinterpret_cast<ushort4*>(&Bst[0][bwr[s]]) = o;
    }
    __syncthreads();
    int buf = 0;
    for (int kt = 0; kt < HH / 32; ++kt) {
      const int nxt = kt + 1;
      const bool more = nxt < HH / 32;
      if (more) {
        const size_t g = (size_t)nxt * (32 * DD);
        #pragma unroll
        for (int s = 0; s < 2; ++s)
          rd[s] = *reinterpret_cast<const float4*>(srcD + g + bgl[s]);
        gl_lds16(hid + abase + nxt * 32, &As[buf ^ 1][0][0] + aoff);
      }
      bf16x8 av[2];
      #pragma unroll
      for (int fm = 0; fm < 2; ++fm) {
        int row = wm + fm * 16 + lr;
        int c = kg ^ ((row >> 1) & 3);
        av[fm] = *reinterpret_cast<const bf16x8*>(&As[buf][row][c * 8]);
      }
      bf16x8 bv0 = trfrag(&Bst[buf][0] + tb0);
      bf16x8 bv1 = trfrag(&Bst[buf][0] + tb1);
      asm volatile("s_waitcnt lgkmcnt(0)" ::: "memory");
      __builtin_amdgcn_sched_barrier(0);
      #pragma unroll
      for (int fm = 0; fm < 2; ++fm) {
        acc[fm][0] = __builtin_amdgcn_mfma_f32_16x16x32_bf16(av[fm], bv0, acc[fm][0], 0, 0, 0);
        acc[fm][1] = __builtin_amdgcn_mfma_f32_16x16x32_bf16(av[fm], bv1, acc[fm][1], 0, 0, 0);
      }
      if (more) {
        #pragma unroll
        for (int s = 0; s < 2; ++s) {
          ushort4 o = { f2bf(rd[s].x), f2bf(rd[s].y), f2bf(rd[s].z), f2bf(rd[s].w) };
          *reinterpret_cast<ushort4*>(&Bst[buf ^ 1][bwr[s]]) = o;
        }
      }
      __syncthreads();
      buf ^= 1;
    }
  } else {
    const int nrow = tid >> 2;
    const int gB = (tid & 3) ^ ((nrow >> 1) & 3);
    const size_t bbase = ((size_t)e * DD + n0 + nrow) * HH + gB * 8;
    const int boff = tid * 8;
    gl_lds16(hid + abase, &As[0][0][0] + aoff);
    gl_lds16(wdT + bbase, &Bst[0][0] + boff);
    __syncthreads();
    int buf = 0;
    for (int kt = 0; kt < HH / 32; ++kt) {
      const int nxt = kt + 1;
      if (nxt < HH / 32) {
        gl_lds16(hid + abase + nxt * 32, &As[buf ^ 1][0][0] + aoff);
        gl_lds16(wdT + bbase + nxt * 32, &Bst[buf ^ 1][0] + boff);
      }
      bf16x8 av[2], bv[2];
      #pragma unroll
      for (int fm = 0; fm < 2; ++fm) {
        int row = wm + fm * 16 + lr;
        int c = kg ^ ((row >> 1) & 3);
        av[fm] = *reinterpret_cast<const bf16x8*>(&As[buf][row][c * 8]);
      }
      #pragma unroll
      for (int fn = 0; fn < 2; ++fn) {
        int row = wn + fn * 16 + lr;
        int c = kg ^ ((row >> 1) & 3);
        bv[fn] = *reinterpret_cast<const bf16x8*>(&Bst[buf][row * 32 + c * 8]);
      }
      #pragma unroll
      for (int fm = 0; fm < 2; ++fm)
        #pragma unroll
        for (int fn = 0; fn < 2; ++fn)
          acc[fm][fn] = __builtin_amdgcn_mfma_f32_16x16x32_bf16(av[fm], bv[fn], acc[fm][fn], 0, 0, 0);
      __syncthreads();
      buf ^= 1;
    }
  }
  #pragma unroll
  for (int fn = 0; fn < 2; ++fn) {
    const int ng = n0 + wn + fn * 16 + lr;
    #pragma unroll
    for (int fm = 0; fm < 2; ++fm) {
      #pragma unroll
      for (int jj = 0; jj < 4; ++jj) {
        int m = mt * 64 + wm + fm * 16 + kg * 4 + jj;
        if (m < ce)
          op[(size_t)(off + m) * DD + ng] = f2bf(acc[fm][fn][jj]);
      }
    }
  }
}

// ---------------- combine + RMSNorm ----------------
__global__ __launch_bounds__(256) void k_norm(
    const unsigned short* __restrict__ op, const int* __restrict__ woff,
    const int* __restrict__ rec, const float* __restrict__ wrec,
    const float* __restrict__ nw, float* __restrict__ out) {
  const int t = blockIdx.x;
  const int tid = threadIdx.x;
  __shared__ float red[4];
  const int e1 = rec[t * 4 + 0], p1 = rec[t * 4 + 1];
  const int e2 = rec[t * 4 + 2], p2 = rec[t * 4 + 3];
  const float w1 = wrec[t * 2 + 0], w2 = wrec[t * 2 + 1];
  const unsigned short* pa = op + (size_t)(woff[e1] + p1) * DD;
  const unsigned short* pb = op + (size_t)(woff[e2] + p2) * DD;
  float v[4]; float ss = 0.f;
  #pragma unroll
  for (int q = 0; q < 4; ++q) {
    int i = q * 256 + tid;
    v[q] = w1 * bf2f(pa[i]) + w2 * bf2f(pb[i]);
    ss += v[q] * v[q];
  }
  #pragma unroll
  for (int o = 32; o > 0; o >>= 1) ss += __shfl_xor(ss, o);
  if ((tid & 63) == 0) red[tid >> 6] = ss;
  __syncthreads();
  const float tot = red[0] + red[1] + red[2] + red[3];
  const float scl = rsqrtf(tot * (1.f / DD) + 1e-6f);
  #pragma unroll
  for (int q = 0; q < 4; ++q) {
    int i = q * 256 + tid;
    out[(size_t)t * DD + i] = v[q] * scl * nw[i];
  }
}

extern "C" void kernel_launch(void* const* d_in, const int* in_sizes, int n_in,
                              void* d_out, int out_size, void* d_ws, size_t ws_size,
                              hipStream_t stream) {
  const float* x      = (const float*)d_in[0];
  const float* rw     = (const float*)d_in[1];
  const float* rb     = (const float*)d_in[2];
  const float* bmag   = (const float*)d_in[3];
  const float* bfreq  = (const float*)d_in[4];
  const float* bphase = (const float*)d_in[5];
  const float* bdown  = (const float*)d_in[6];
  const float* nw     = (const float*)d_in[7];
  float* out = (float*)d_out;
  char* ws = (char*)d_ws;
  const size_t MB = 1024 * 1024;
  int*   cnt    = (int*)(ws + 0);          // 16 int
  int*   work1  = (int*)(ws + 128);        // WM128*2 int
  int*   work2  = (int*)(ws + 1024);       // WM64*2 int
  int*   woff   = (int*)(ws + 2048);       // 16 int
  int*   pm     = (int*)(ws + 3072);       // [0]=mode, [8..71]=p0 per lane, [80..87]=dtab
  int*   list   = (int*)(ws + 4096);       // 16*2048 int
  int*   rec    = (int*)(ws + 139264);     // 2048*4 int
  float* wrec   = (float*)(ws + 172032);   // 2048*2 f32
  unsigned short* xbf = (unsigned short*)(ws + 1 * MB);    // 4 MB
  unsigned short* hid = (unsigned short*)(ws + 5 * MB);    // 16 MB
  unsigned short* op  = (unsigned short*)(ws + 21 * MB);   // 8 MB
  unsigned short* wmT = (unsigned short*)(ws + 32 * MB);   // 64 MB (fallback; reused by wdT)
  unsigned short* wfT = (unsigned short*)(ws + 96 * MB);   // 64 MB (fallback)
  unsigned short* wdT = wmT;                               // alias (fallback, after k_up)

  hipMemsetAsync(cnt, 0, 64, stream);
  k_probe<<<1, 64, 0, stream>>>(pm);
  k_cvt_x<<<1024, 256, 0, stream>>>(x, xbf);
  k_router<<<TT, 256, 0, stream>>>(x, rw, rb, cnt, list, rec, wrec);
  k_sched<<<1, 64, 0, stream>>>(cnt, work1, work2, woff);
  // fallback-only transposes (early-exit if fused path verified)
  k_trans<<<dim3(HH / 64, DD / 64, 32), 256, 0, stream>>>(bmag, bfreq, wmT, wfT, DD, HH, pm);
  k_up<<<dim3(WM128, HH / 64), 256, 0, stream>>>(xbf, bmag, bfreq, wmT, wfT, bphase,
                                                 cnt, list, work1, woff, pm, hid);
  k_trans<<<dim3(DD / 64, HH / 64, 16), 256, 0, stream>>>(bdown, bdown, wdT, wdT, HH, DD, pm);
  k_down<<<dim3(WM64, DD / 64), 256, 0, stream>>>(hid, bdown, wdT, cnt, work2, woff, pm, op);
  k_norm<<<TT, 256, 0, stream>>>(op, woff, rec, wrec, nw, out);
}

// Round 9
// 318.242 us; speedup vs baseline: 1.0554x; 1.0554x over previous
//
#include <hip/hip_runtime.h>
#include <hip/hip_bf16.h>
#include <cstdint>
#include <cstddef>

#define TT 2048      // tokens (b*t)
#define DD 1024      // d
#define HH 2048      // h
#define NE 16        // experts
#define WM128 48     // max (expert, 128-row block) work items
#define WM64  80     // max (expert, 64-row block) work items
#define BROW 17      // B-tile row stride in u32 (64 rows x 17): 2-way-free banks both sides

typedef __bf16 bf16x8 __attribute__((ext_vector_type(8)));
typedef float f32x4 __attribute__((ext_vector_type(4)));

__device__ __forceinline__ unsigned short f2bf(float f) {
  union { float f; unsigned u; } v; v.f = f;
  unsigned r = (v.u + 0x7FFFu + ((v.u >> 16) & 1u)) >> 16;  // RNE
  return (unsigned short)r;
}
__device__ __forceinline__ float bf2f(unsigned short s) {
  union { unsigned u; float f; } v; v.u = ((unsigned)s) << 16;
  return v.f;
}
__device__ __forceinline__ unsigned packbf(float lo, float hi) {
  return (unsigned)f2bf(lo) | ((unsigned)f2bf(hi) << 16);
}

__device__ __forceinline__ void gl_lds16(const void* g, void* l) {
  __builtin_amdgcn_global_load_lds(
      (const __attribute__((address_space(1))) unsigned int*)g,
      (__attribute__((address_space(3))) unsigned int*)l, 16, 0, 0);
}

union U4 { unsigned int u[4]; bf16x8 v; };

// ---------------- x fp32 -> bf16 ----------------
__global__ __launch_bounds__(256) void k_cvt_x(const float* __restrict__ x,
                                               unsigned short* __restrict__ xbf) {
  int i = blockIdx.x * 256 + threadIdx.x;
  const float4* p = reinterpret_cast<const float4*>(x) + (size_t)i * 2;
  float4 a = p[0], b = p[1];
  ushort4 o0 = { f2bf(a.x), f2bf(a.y), f2bf(a.z), f2bf(a.w) };
  ushort4 o1 = { f2bf(b.x), f2bf(b.y), f2bf(b.z), f2bf(b.w) };
  reinterpret_cast<ushort4*>(xbf)[(size_t)i * 2]     = o0;
  reinterpret_cast<ushort4*>(xbf)[(size_t)i * 2 + 1] = o1;
}

// ---------------- router + top-2 + bucketing ----------------
__global__ __launch_bounds__(256) void k_router(
    const float* __restrict__ x, const float* __restrict__ rw,
    const float* __restrict__ rb, int* __restrict__ cnt,
    int* __restrict__ list_tok, int* __restrict__ rec,
    float* __restrict__ wrec) {
  const int t = blockIdx.x;
  __shared__ float xs[DD];
  __shared__ float part[256];
  __shared__ float sc[NE];
  const float* xr = x + (size_t)t * DD;
  for (int i = threadIdx.x; i < DD; i += 256) xs[i] = xr[i];
  __syncthreads();
  const int e = threadIdx.x >> 4, j = threadIdx.x & 15;
  const float* w = rw + (size_t)e * DD;
  float s = 0.f;
  for (int i = j; i < DD; i += 16) s += xs[i] * w[i];
  part[threadIdx.x] = s;
  __syncthreads();
  if (threadIdx.x < NE) {
    float v = rb[threadIdx.x];
    #pragma unroll
    for (int q = 0; q < 16; ++q) v += part[threadIdx.x * 16 + q];
    sc[threadIdx.x] = v;
  }
  __syncthreads();
  if (threadIdx.x == 0) {
    int e1 = 0; float v1 = sc[0];
    #pragma unroll
    for (int q = 1; q < NE; ++q) { if (sc[q] > v1) { v1 = sc[q]; e1 = q; } }
    int e2 = -1; float v2 = -3.4e38f;
    #pragma unroll
    for (int q = 0; q < NE; ++q) {
      if (q != e1 && sc[q] > v2) { v2 = sc[q]; e2 = q; }
    }
    float ex = expf(v2 - v1);
    float w1 = 1.f / (1.f + ex);
    float w2 = ex / (1.f + ex);
    int p1 = atomicAdd(&cnt[e1], 1);
    int p2 = atomicAdd(&cnt[e2], 1);
    list_tok[e1 * TT + p1] = t;
    list_tok[e2 * TT + p2] = t;
    rec[t * 4 + 0] = e1; rec[t * 4 + 1] = p1;
    rec[t * 4 + 2] = e2; rec[t * 4 + 3] = p2;
    wrec[t * 2 + 0] = w1; wrec[t * 2 + 1] = w2;
  }
}

// ---------------- work-table builder ----------------
__global__ void k_sched(const int* __restrict__ cnt, int* __restrict__ work128,
                        int* __restrict__ work64, int* __restrict__ woff) {
  if (threadIdx.x == 0) {
    int o = 0, n1 = 0, n2 = 0;
    for (int e = 0; e < NE; ++e) {
      int ce = cnt[e];
      int a = (ce + 127) >> 7;
      for (int mb = 0; mb < a; ++mb) { work128[n1 * 2] = e; work128[n1 * 2 + 1] = mb; ++n1; }
      int b = (ce + 63) >> 6;
      for (int mb = 0; mb < b; ++mb) { work64[n2 * 2] = e; work64[n2 * 2 + 1] = mb; ++n2; }
      woff[e] = o; o += ce;
    }
    for (int q = n1; q < WM128; ++q) { work128[q * 2] = -1; work128[q * 2 + 1] = 0; }
    for (int q = n2; q < WM64; ++q)  { work64[q * 2] = -1;  work64[q * 2 + 1] = 0; }
  }
}

// ---------------- up GEMMs (mag,freq) + activation — fused fp32-weight path ----------------
// BM=128, BN=64, BK=32, 4 waves 2x2 of 64x32. A: bf16 gl_lds (proven R5 path).
// B: fp32 [32k][64n] tile -> reg -> pack (k,k+1) u32 -> [n][BROW] LDS -> b32 frag reads.
__global__ __launch_bounds__(256, 4) void k_up(
    const unsigned short* __restrict__ xbf,
    const float* __restrict__ bmag,    // [e][DD][HH]
    const float* __restrict__ bfreq,   // [e][DD][HH]
    const float* __restrict__ bphase,
    const int* __restrict__ cnt, const int* __restrict__ list_tok,
    const int* __restrict__ work, const int* __restrict__ woff,
    unsigned short* __restrict__ hid) {
  const int e = work[blockIdx.x * 2 + 0];
  if (e < 0) return;
  const int mt = work[blockIdx.x * 2 + 1];
  const int nt = blockIdx.y;
  const int ce = cnt[e];
  const int off = woff[e];
  __shared__ unsigned short As[2][128][32];   // 16 KB
  __shared__ unsigned int BuM[2][64 * BROW];  // 8.5 KB
  __shared__ unsigned int BuF[2][64 * BROW];  // 8.5 KB
  __shared__ int toks[128];
  const int tid = threadIdx.x;
  if (tid < 128) {
    int r = mt * 128 + tid;
    toks[tid] = list_tok[e * TT + (r < ce ? r : ce - 1)];
  }
  __syncthreads();
  const int w = tid >> 6, l = tid & 63;
  // ---- A staging (2 x gl_lds16/thread, source chunk swizzle) ----
  size_t abase[2]; int aoff[2];
  #pragma unroll
  for (int p = 0; p < 2; ++p) {
    int row = p * 64 + w * 16 + (l >> 2);
    int g = (l & 3) ^ ((row >> 1) & 3);
    abase[p] = (size_t)toks[row] * DD + g * 8;
    aoff[p] = (p * 256 + w * 64 + l) * 8;
  }
  // ---- B staging mapping: thread -> (k-pair q, n-quad b16) ----
  const int q = tid >> 4;       // 0..15 -> k = 2q, 2q+1
  const int b16 = tid & 15;     // n = 4*b16 .. +3
  const int n0 = nt * 64;
  const float* srcM = bmag  + (size_t)e * DD * HH + n0 + 4 * b16;
  const float* srcF = bfreq + (size_t)e * DD * HH + n0 + 4 * b16;
  int bw[4];
  #pragma unroll
  for (int i = 0; i < 4; ++i) bw[i] = (4 * b16 + i) * BROW + q;

  const int wm = (w >> 1) * 64, wn = (w & 1) * 32;
  const int lr = l & 15, kg = l >> 4;
  const int nb0 = (wn + lr) * BROW + kg * 4;        // fn=0 frag base (u32)
  const int nb1 = (wn + 16 + lr) * BROW + kg * 4;   // fn=1
  const f32x4 zero = {0.f, 0.f, 0.f, 0.f};
  f32x4 accM[4][2], accF[4][2];
  #pragma unroll
  for (int a = 0; a < 4; ++a)
    #pragma unroll
    for (int b = 0; b < 2; ++b) { accM[a][b] = zero; accF[a][b] = zero; }

  float4 rm0, rm1, rf0, rf1;
  auto loadB = [&](int kt) {
    const float* pM = srcM + (size_t)(kt * 32 + 2 * q) * HH;
    const float* pF = srcF + (size_t)(kt * 32 + 2 * q) * HH;
    rm0 = *reinterpret_cast<const float4*>(pM);
    rm1 = *reinterpret_cast<const float4*>(pM + HH);
    rf0 = *reinterpret_cast<const float4*>(pF);
    rf1 = *reinterpret_cast<const float4*>(pF + HH);
  };
  auto writeB = [&](int buf) {
    const float* m0 = reinterpret_cast<const float*>(&rm0);
    const float* m1 = reinterpret_cast<const float*>(&rm1);
    const float* f0 = reinterpret_cast<const float*>(&rf0);
    const float* f1 = reinterpret_cast<const float*>(&rf1);
    #pragma unroll
    for (int i = 0; i < 4; ++i) {
      BuM[buf][bw[i]] = packbf(m0[i], m1[i]);
      BuF[buf][bw[i]] = packbf(f0[i], f1[i]);
    }
  };

  // prologue
  loadB(0);
  #pragma unroll
  for (int p = 0; p < 2; ++p) gl_lds16(xbf + abase[p], &As[0][0][0] + aoff[p]);
  writeB(0);
  __syncthreads();
  int buf = 0;
  for (int kt = 0; kt < DD / 32; ++kt) {
    const bool more = (kt + 1) < DD / 32;
    if (more) {
      loadB(kt + 1);                 // issue early (T14): hidden under compute
      #pragma unroll
      for (int p = 0; p < 2; ++p)
        gl_lds16(xbf + abase[p] + (kt + 1) * 32, &As[buf ^ 1][0][0] + aoff[p]);
    }
    // ---- compute current buffer ----
    bf16x8 av[4];
    #pragma unroll
    for (int fm = 0; fm < 4; ++fm) {
      int row = wm + fm * 16 + lr;
      int c = kg ^ ((row >> 1) & 3);
      av[fm] = *reinterpret_cast<const bf16x8*>(&As[buf][row][c * 8]);
    }
    U4 tm0, tm1, tf0, tf1;
    const unsigned int* bm = &BuM[buf][0];
    const unsigned int* bfp = &BuF[buf][0];
    #pragma unroll
    for (int j2 = 0; j2 < 4; ++j2) {
      tm0.u[j2] = bm[nb0 + j2];  tm1.u[j2] = bm[nb1 + j2];
      tf0.u[j2] = bfp[nb0 + j2]; tf1.u[j2] = bfp[nb1 + j2];
    }
    #pragma unroll
    for (int fm = 0; fm < 4; ++fm) {
      accM[fm][0] = __builtin_amdgcn_mfma_f32_16x16x32_bf16(av[fm], tm0.v, accM[fm][0], 0, 0, 0);
      accM[fm][1] = __builtin_amdgcn_mfma_f32_16x16x32_bf16(av[fm], tm1.v, accM[fm][1], 0, 0, 0);
      accF[fm][0] = __builtin_amdgcn_mfma_f32_16x16x32_bf16(av[fm], tf0.v, accF[fm][0], 0, 0, 0);
      accF[fm][1] = __builtin_amdgcn_mfma_f32_16x16x32_bf16(av[fm], tf1.v, accF[fm][1], 0, 0, 0);
    }
    if (more) writeB(buf ^ 1);       // cvt+store after compute (loads have landed)
    __syncthreads();
    buf ^= 1;
  }
  // ---- epilogue: activation + store ----
  #pragma unroll
  for (int fn = 0; fn < 2; ++fn) {
    const int ng = n0 + wn + fn * 16 + lr;
    const float ph = bphase[e * HH + ng] + 0.1f;
    #pragma unroll
    for (int fm = 0; fm < 4; ++fm) {
      #pragma unroll
      for (int jj = 0; jj < 4; ++jj) {
        int m = mt * 128 + wm + fm * 16 + kg * 4 + jj;
        if (m < ce) {
          float mv = (fn == 0) ? accM[fm][0][jj] : accM[fm][1][jj];
          float fv = (fn == 0) ? accF[fm][0][jj] : accF[fm][1][jj];
          float exn = __expf(-fabsf(fv));
          float sp = fmaxf(fv, 0.f) + __logf(1.f + exn);   // stable softplus
          float t2 = __expf(2.f * mv);
          float th = 1.f - 2.f / (t2 + 1.f);               // tanh
          float hv = th * __cosf(sp + ph);
          hid[(size_t)(off + m) * HH + ng] = f2bf(hv);
        }
      }
    }
  }
}

// ---------------- down GEMM — fused fp32-weight path ----------------
// BM=64, BN=64, BK=32, 4 waves 2x2 of 32x32.
__global__ __launch_bounds__(256, 4) void k_down(
    const unsigned short* __restrict__ hid,
    const float* __restrict__ bdown,   // [e][HH][DD]
    const int* __restrict__ cnt,
    const int* __restrict__ work, const int* __restrict__ woff,
    unsigned short* __restrict__ op) {
  const int e = work[blockIdx.x * 2 + 0];
  if (e < 0) return;
  const int mt = work[blockIdx.x * 2 + 1];
  const int nt = blockIdx.y;
  const int ce = cnt[e];
  const int off = woff[e];
  __shared__ unsigned short As[2][64][32];    // 8 KB
  __shared__ unsigned int Bu[2][64 * BROW];   // 8.5 KB
  const int tid = threadIdx.x;
  const int w = tid >> 6, l = tid & 63;
  // A staging (1 gl_lds/thread; proven R8 path)
  const int row0 = tid >> 2;
  int gr = mt * 64 + row0; if (gr >= ce) gr = ce - 1;
  const size_t abase = (size_t)(off + gr) * HH + (size_t)(((tid & 3) ^ ((row0 >> 1) & 3)) * 8);
  const int aoff = tid * 8;
  // B staging mapping
  const int q = tid >> 4;
  const int b16 = tid & 15;
  const int n0 = nt * 64;
  const float* srcD = bdown + (size_t)e * HH * DD + n0 + 4 * b16;
  int bw[4];
  #pragma unroll
  for (int i = 0; i < 4; ++i) bw[i] = (4 * b16 + i) * BROW + q;

  const int wm = (w >> 1) * 32, wn = (w & 1) * 32;
  const int lr = l & 15, kg = l >> 4;
  const int nb0 = (wn + lr) * BROW + kg * 4;
  const int nb1 = (wn + 16 + lr) * BROW + kg * 4;
  const f32x4 zero = {0.f, 0.f, 0.f, 0.f};
  f32x4 acc[2][2];
  #pragma unroll
  for (int a = 0; a < 2; ++a)
    #pragma unroll
    for (int b = 0; b < 2; ++b) acc[a][b] = zero;

  float4 rd0, rd1;
  auto loadB = [&](int kt) {
    const float* pD = srcD + (size_t)(kt * 32 + 2 * q) * DD;
    rd0 = *reinterpret_cast<const float4*>(pD);
    rd1 = *reinterpret_cast<const float4*>(pD + DD);
  };
  auto writeB = [&](int buf) {
    const float* d0 = reinterpret_cast<const float*>(&rd0);
    const float* d1 = reinterpret_cast<const float*>(&rd1);
    #pragma unroll
    for (int i = 0; i < 4; ++i) Bu[buf][bw[i]] = packbf(d0[i], d1[i]);
  };

  loadB(0);
  gl_lds16(hid + abase, &As[0][0][0] + aoff);
  writeB(0);
  __syncthreads();
  int buf = 0;
  for (int kt = 0; kt < HH / 32; ++kt) {
    const bool more = (kt + 1) < HH / 32;
    if (more) {
      loadB(kt + 1);
      gl_lds16(hid + abase + (kt + 1) * 32, &As[buf ^ 1][0][0] + aoff);
    }
    bf16x8 av[2];
    #pragma unroll
    for (int fm = 0; fm < 2; ++fm) {
      int row = wm + fm * 16 + lr;
      int c = kg ^ ((row >> 1) & 3);
      av[fm] = *reinterpret_cast<const bf16x8*>(&As[buf][row][c * 8]);
    }
    U4 t0, t1;
    const unsigned int* bp = &Bu[buf][0];
    #pragma unroll
    for (int j2 = 0; j2 < 4; ++j2) { t0.u[j2] = bp[nb0 + j2]; t1.u[j2] = bp[nb1 + j2]; }
    #pragma unroll
    for (int fm = 0; fm < 2; ++fm) {
      acc[fm][0] = __builtin_amdgcn_mfma_f32_16x16x32_bf16(av[fm], t0.v, acc[fm][0], 0, 0, 0);
      acc[fm][1] = __builtin_amdgcn_mfma_f32_16x16x32_bf16(av[fm], t1.v, acc[fm][1], 0, 0, 0);
    }
    if (more) writeB(buf ^ 1);
    __syncthreads();
    buf ^= 1;
  }
  #pragma unroll
  for (int fn = 0; fn < 2; ++fn) {
    const int ng = n0 + wn + fn * 16 + lr;
    #pragma unroll
    for (int fm = 0; fm < 2; ++fm) {
      #pragma unroll
      for (int jj = 0; jj < 4; ++jj) {
        int m = mt * 64 + wm + fm * 16 + kg * 4 + jj;
        if (m < ce)
          op[(size_t)(off + m) * DD + ng] = f2bf(acc[fm][fn][jj]);
      }
    }
  }
}

// ---------------- combine + RMSNorm ----------------
__global__ __launch_bounds__(256) void k_norm(
    const unsigned short* __restrict__ op, const int* __restrict__ woff,
    const int* __restrict__ rec, const float* __restrict__ wrec,
    const float* __restrict__ nw, float* __restrict__ out) {
  const int t = blockIdx.x;
  const int tid = threadIdx.x;
  __shared__ float red[4];
  const int e1 = rec[t * 4 + 0], p1 = rec[t * 4 + 1];
  const int e2 = rec[t * 4 + 2], p2 = rec[t * 4 + 3];
  const float w1 = wrec[t * 2 + 0], w2 = wrec[t * 2 + 1];
  const unsigned short* pa = op + (size_t)(woff[e1] + p1) * DD;
  const unsigned short* pb = op + (size_t)(woff[e2] + p2) * DD;
  float v[4]; float ss = 0.f;
  #pragma unroll
  for (int q = 0; q < 4; ++q) {
    int i = q * 256 + tid;
    v[q] = w1 * bf2f(pa[i]) + w2 * bf2f(pb[i]);
    ss += v[q] * v[q];
  }
  #pragma unroll
  for (int o = 32; o > 0; o >>= 1) ss += __shfl_xor(ss, o);
  if ((tid & 63) == 0) red[tid >> 6] = ss;
  __syncthreads();
  const float tot = red[0] + red[1] + red[2] + red[3];
  const float scl = rsqrtf(tot * (1.f / DD) + 1e-6f);
  #pragma unroll
  for (int q = 0; q < 4; ++q) {
    int i = q * 256 + tid;
    out[(size_t)t * DD + i] = v[q] * scl * nw[i];
  }
}

extern "C" void kernel_launch(void* const* d_in, const int* in_sizes, int n_in,
                              void* d_out, int out_size, void* d_ws, size_t ws_size,
                              hipStream_t stream) {
  const float* x      = (const float*)d_in[0];
  const float* rw     = (const float*)d_in[1];
  const float* rb     = (const float*)d_in[2];
  const float* bmag   = (const float*)d_in[3];
  const float* bfreq  = (const float*)d_in[4];
  const float* bphase = (const float*)d_in[5];
  const float* bdown  = (const float*)d_in[6];
  const float* nw     = (const float*)d_in[7];
  float* out = (float*)d_out;
  char* ws = (char*)d_ws;
  const size_t MB = 1024 * 1024;
  int*   cnt    = (int*)(ws + 0);          // 16 int
  int*   work1  = (int*)(ws + 128);        // WM128*2 int
  int*   work2  = (int*)(ws + 1024);       // WM64*2 int
  int*   woff   = (int*)(ws + 2048);       // 16 int
  int*   list   = (int*)(ws + 4096);       // 16*2048 int
  int*   rec    = (int*)(ws + 139264);     // 2048*4 int
  float* wrec   = (float*)(ws + 172032);   // 2048*2 f32
  unsigned short* xbf = (unsigned short*)(ws + 1 * MB);    // 4 MB
  unsigned short* hid = (unsigned short*)(ws + 5 * MB);    // 16 MB
  unsigned short* op  = (unsigned short*)(ws + 21 * MB);   // 8 MB

  hipMemsetAsync(cnt, 0, 64, stream);
  k_cvt_x<<<1024, 256, 0, stream>>>(x, xbf);
  k_router<<<TT, 256, 0, stream>>>(x, rw, rb, cnt, list, rec, wrec);
  k_sched<<<1, 64, 0, stream>>>(cnt, work1, work2, woff);
  k_up<<<dim3(WM128, HH / 64), 256, 0, stream>>>(xbf, bmag, bfreq, bphase,
                                                 cnt, list, work1, woff, hid);
  k_down<<<dim3(WM64, DD / 64), 256, 0, stream>>>(hid, bdown, cnt, work2, woff, op);
  k_norm<<<TT, 256, 0, stream>>>(op, woff, rec, wrec, nw, out);
}

// Round 10
// 294.732 us; speedup vs baseline: 1.1396x; 1.0798x over previous
//
#include <hip/hip_runtime.h>
#include <hip/hip_bf16.h>
#include <cstdint>
#include <cstddef>

#define TT 2048      // tokens (b*t)
#define DD 1024      // d
#define HH 2048      // h
#define NE 16        // experts
#define WM128 48     // max (expert, 128-row block) work items
#define BW35 35      // B-tile row stride in u32 (64 rows x 35): 2-way-free banks both sides

typedef __bf16 bf16x8 __attribute__((ext_vector_type(8)));
typedef float f32x4 __attribute__((ext_vector_type(4)));

__device__ __forceinline__ unsigned short f2bf(float f) {
  union { float f; unsigned u; } v; v.f = f;
  unsigned r = (v.u + 0x7FFFu + ((v.u >> 16) & 1u)) >> 16;  // RNE
  return (unsigned short)r;
}
__device__ __forceinline__ float bf2f(unsigned short s) {
  union { unsigned u; float f; } v; v.u = ((unsigned)s) << 16;
  return v.f;
}
__device__ __forceinline__ unsigned packbf(float lo, float hi) {
  return (unsigned)f2bf(lo) | ((unsigned)f2bf(hi) << 16);
}

__device__ __forceinline__ void gl_lds16(const void* g, void* l) {
  __builtin_amdgcn_global_load_lds(
      (const __attribute__((address_space(1))) unsigned int*)g,
      (__attribute__((address_space(3))) unsigned int*)l, 16, 0, 0);
}

union U4 { unsigned int u[4]; bf16x8 v; };

// ---------------- router + top-2 + bucketing + x cvt (fused) ----------------
__global__ __launch_bounds__(256) void k_router(
    const float* __restrict__ x, const float* __restrict__ rw,
    const float* __restrict__ rb, int* __restrict__ cnt,
    int* __restrict__ list_tok, int* __restrict__ rec,
    float* __restrict__ wrec, unsigned short* __restrict__ xbf) {
  const int t = blockIdx.x;
  __shared__ float xs[DD];
  __shared__ float part[256];
  __shared__ float sc[NE];
  const float* xr = x + (size_t)t * DD;
  for (int i = threadIdx.x; i < DD; i += 256) xs[i] = xr[i];
  __syncthreads();
  // fused x -> bf16 (xs is stable after the barrier)
  {
    int i = threadIdx.x * 4;
    ushort4 o = { f2bf(xs[i]), f2bf(xs[i + 1]), f2bf(xs[i + 2]), f2bf(xs[i + 3]) };
    *reinterpret_cast<ushort4*>(xbf + (size_t)t * DD + i) = o;
  }
  const int e = threadIdx.x >> 4, j = threadIdx.x & 15;
  const float* w = rw + (size_t)e * DD;
  float s = 0.f;
  for (int i = j; i < DD; i += 16) s += xs[i] * w[i];
  part[threadIdx.x] = s;
  __syncthreads();
  if (threadIdx.x < NE) {
    float v = rb[threadIdx.x];
    #pragma unroll
    for (int q = 0; q < 16; ++q) v += part[threadIdx.x * 16 + q];
    sc[threadIdx.x] = v;
  }
  __syncthreads();
  if (threadIdx.x == 0) {
    int e1 = 0; float v1 = sc[0];
    #pragma unroll
    for (int q = 1; q < NE; ++q) { if (sc[q] > v1) { v1 = sc[q]; e1 = q; } }
    int e2 = -1; float v2 = -3.4e38f;
    #pragma unroll
    for (int q = 0; q < NE; ++q) {
      if (q != e1 && sc[q] > v2) { v2 = sc[q]; e2 = q; }
    }
    float ex = expf(v2 - v1);
    float w1 = 1.f / (1.f + ex);
    float w2 = ex / (1.f + ex);
    int p1 = atomicAdd(&cnt[e1], 1);
    int p2 = atomicAdd(&cnt[e2], 1);
    list_tok[e1 * TT + p1] = t;
    list_tok[e2 * TT + p2] = t;
    rec[t * 4 + 0] = e1; rec[t * 4 + 1] = p1;
    rec[t * 4 + 2] = e2; rec[t * 4 + 3] = p2;
    wrec[t * 2 + 0] = w1; wrec[t * 2 + 1] = w2;
  }
}

// ---------------- work-table builder ----------------
__global__ void k_sched(const int* __restrict__ cnt, int* __restrict__ work128,
                        int* __restrict__ woff) {
  if (threadIdx.x == 0) {
    int o = 0, n1 = 0;
    for (int e = 0; e < NE; ++e) {
      int ce = cnt[e];
      int a = (ce + 127) >> 7;
      for (int mb = 0; mb < a; ++mb) { work128[n1 * 2] = e; work128[n1 * 2 + 1] = mb; ++n1; }
      woff[e] = o; o += ce;
    }
    for (int q = n1; q < WM128; ++q) { work128[q * 2] = -1; work128[q * 2 + 1] = 0; }
  }
}

// ---------------- up GEMMs (mag,freq) + activation — fused fp32-weight path ----------------
// BM=128, BN=64, BK=64, 4 waves 2x2 of 64x32. A: bf16 gl_lds (R5 BKW=64 proven path).
// B: fp32 [64k][64n] tile -> reg -> pack (k,k+1) u32 -> [n][BW35] LDS -> b32 frag reads.
// 32 MFMA per barrier (compute phase ~ HBM latency); 16 iterations.
__global__ __launch_bounds__(256, 2) void k_up(
    const unsigned short* __restrict__ xbf,
    const float* __restrict__ bmag,    // [e][DD][HH]
    const float* __restrict__ bfreq,   // [e][DD][HH]
    const float* __restrict__ bphase,
    const int* __restrict__ cnt, const int* __restrict__ list_tok,
    const int* __restrict__ work, const int* __restrict__ woff,
    unsigned short* __restrict__ hid) {
  const int e = work[blockIdx.x * 2 + 0];
  if (e < 0) return;
  const int mt = work[blockIdx.x * 2 + 1];
  const int nt = blockIdx.y;
  const int ce = cnt[e];
  const int off = woff[e];
  __shared__ unsigned short As[2][128][64];    // 32 KB
  __shared__ unsigned int BuM[2][64 * BW35];   // 17.5 KB
  __shared__ unsigned int BuF[2][64 * BW35];   // 17.5 KB
  __shared__ int toks[128];
  const int tid = threadIdx.x;
  if (tid < 128) {
    int r = mt * 128 + tid;
    toks[tid] = list_tok[e * TT + (r < ce ? r : ce - 1)];
  }
  __syncthreads();
  const int w = tid >> 6, l = tid & 63;
  const int lhi = l >> 3, llo = l & 7;
  // ---- A staging: 4 x gl_lds16/thread, source chunk swizzle (R3/R5 proven) ----
  size_t abase[4]; int aoff[4];
  #pragma unroll
  for (int j = 0; j < 4; ++j) {
    int seg = w * 4 + j;
    int r = seg * 8 + lhi;
    abase[j] = (size_t)toks[r] * DD + (size_t)((llo ^ (r & 7)) * 8);
    aoff[j] = seg * 512 + l * 8;
  }
  // ---- B staging: thread s-slot -> (k-pair q2, n-quad b16) ----
  const int n0 = nt * 64;
  const float* srcM = bmag  + (size_t)e * DD * HH + n0 + 4 * (tid & 15);
  const float* srcF = bfreq + (size_t)e * DD * HH + n0 + 4 * (tid & 15);
  int q2s[2], bw[2][4];
  #pragma unroll
  for (int s = 0; s < 2; ++s) {
    int idx = s * 256 + tid;
    int q2 = idx >> 4;              // k-pair 0..31
    q2s[s] = q2;
    #pragma unroll
    for (int i = 0; i < 4; ++i) bw[s][i] = (4 * (tid & 15) + i) * BW35 + q2;
  }
  const int wm = (w >> 1) * 64, wn = (w & 1) * 32;
  const int lr = l & 15, kg = l >> 4;
  const f32x4 zero = {0.f, 0.f, 0.f, 0.f};
  f32x4 accM[4][2], accF[4][2];
  #pragma unroll
  for (int a = 0; a < 4; ++a)
    #pragma unroll
    for (int b = 0; b < 2; ++b) { accM[a][b] = zero; accF[a][b] = zero; }

  float4 rm0[2], rm1[2], rf0[2], rf1[2];
  auto loadB = [&](int kt) {
    #pragma unroll
    for (int s = 0; s < 2; ++s) {
      const float* pM = srcM + (size_t)(kt * 64 + 2 * q2s[s]) * HH;
      const float* pF = srcF + (size_t)(kt * 64 + 2 * q2s[s]) * HH;
      rm0[s] = *reinterpret_cast<const float4*>(pM);
      rm1[s] = *reinterpret_cast<const float4*>(pM + HH);
      rf0[s] = *reinterpret_cast<const float4*>(pF);
      rf1[s] = *reinterpret_cast<const float4*>(pF + HH);
    }
  };
  auto writeB = [&](int buf) {
    #pragma unroll
    for (int s = 0; s < 2; ++s) {
      const float* m0 = reinterpret_cast<const float*>(&rm0[s]);
      const float* m1 = reinterpret_cast<const float*>(&rm1[s]);
      const float* f0 = reinterpret_cast<const float*>(&rf0[s]);
      const float* f1 = reinterpret_cast<const float*>(&rf1[s]);
      #pragma unroll
      for (int i = 0; i < 4; ++i) {
        BuM[buf][bw[s][i]] = packbf(m0[i], m1[i]);
        BuF[buf][bw[s][i]] = packbf(f0[i], f1[i]);
      }
    }
  };

  // prologue
  loadB(0);
  #pragma unroll
  for (int j = 0; j < 4; ++j) gl_lds16(xbf + abase[j], &As[0][0][0] + aoff[j]);
  writeB(0);
  __syncthreads();
  int buf = 0;
  for (int kt = 0; kt < DD / 64; ++kt) {
    const bool more = (kt + 1) < DD / 64;
    if (more) {
      #pragma unroll
      for (int j = 0; j < 4; ++j)
        gl_lds16(xbf + abase[j] + (kt + 1) * 64, &As[buf ^ 1][0][0] + aoff[j]);
      loadB(kt + 1);                 // issue early; lands during the 32-MFMA phase
    }
    // ---- compute current buffer: 2 K-slices x (4 fm x 2 fn x 2 mats) ----
    #pragma unroll
    for (int ks = 0; ks < 2; ++ks) {
      bf16x8 av[4];
      #pragma unroll
      for (int fm = 0; fm < 4; ++fm) {
        int row = wm + fm * 16 + lr;
        int c = (ks * 4 + kg) ^ (row & 7);
        av[fm] = *reinterpret_cast<const bf16x8*>(&As[buf][row][c * 8]);
      }
      U4 tm[2], tf[2];
      #pragma unroll
      for (int fn = 0; fn < 2; ++fn) {
        const int nb = (wn + fn * 16 + lr) * BW35 + ks * 16 + kg * 4;
        #pragma unroll
        for (int j2 = 0; j2 < 4; ++j2) {
          tm[fn].u[j2] = BuM[buf][nb + j2];
          tf[fn].u[j2] = BuF[buf][nb + j2];
        }
      }
      #pragma unroll
      for (int fm = 0; fm < 4; ++fm)
        #pragma unroll
        for (int fn = 0; fn < 2; ++fn) {
          accM[fm][fn] = __builtin_amdgcn_mfma_f32_16x16x32_bf16(av[fm], tm[fn].v, accM[fm][fn], 0, 0, 0);
          accF[fm][fn] = __builtin_amdgcn_mfma_f32_16x16x32_bf16(av[fm], tf[fn].v, accF[fm][fn], 0, 0, 0);
        }
    }
    if (more) writeB(buf ^ 1);       // cvt+store after compute (loads have landed)
    __syncthreads();
    buf ^= 1;
  }
  // ---- epilogue: activation + store ----
  #pragma unroll
  for (int fn = 0; fn < 2; ++fn) {
    const int ng = n0 + wn + fn * 16 + lr;
    const float ph = bphase[e * HH + ng] + 0.1f;
    #pragma unroll
    for (int fm = 0; fm < 4; ++fm) {
      #pragma unroll
      for (int jj = 0; jj < 4; ++jj) {
        int m = mt * 128 + wm + fm * 16 + kg * 4 + jj;
        if (m < ce) {
          float mv = accM[fm][fn][jj];
          float fv = accF[fm][fn][jj];
          float exn = __expf(-fabsf(fv));
          float sp = fmaxf(fv, 0.f) + __logf(1.f + exn);   // stable softplus
          float t2 = __expf(2.f * mv);
          float th = 1.f - 2.f / (t2 + 1.f);               // tanh
          float hv = th * __cosf(sp + ph);
          hid[(size_t)(off + m) * HH + ng] = f2bf(hv);
        }
      }
    }
  }
}

// ---------------- down GEMM — fused fp32-weight path ----------------
// BM=128, BN=64, BK=64, 4 waves 2x2 of 64x32; 32 iterations, 16 MFMA/iter.
__global__ __launch_bounds__(256, 3) void k_down(
    const unsigned short* __restrict__ hid,
    const float* __restrict__ bdown,   // [e][HH][DD]
    const int* __restrict__ cnt,
    const int* __restrict__ work, const int* __restrict__ woff,
    unsigned short* __restrict__ op) {
  const int e = work[blockIdx.x * 2 + 0];
  if (e < 0) return;
  const int mt = work[blockIdx.x * 2 + 1];
  const int nt = blockIdx.y;
  const int ce = cnt[e];
  const int off = woff[e];
  __shared__ unsigned short As[2][128][64];    // 32 KB
  __shared__ unsigned int Bu[2][64 * BW35];    // 17.5 KB
  const int tid = threadIdx.x;
  const int w = tid >> 6, l = tid & 63;
  const int lhi = l >> 3, llo = l & 7;
  // A staging: 4 gl_lds/thread (hid bf16 rows)
  size_t abase[4]; int aoff[4];
  #pragma unroll
  for (int j = 0; j < 4; ++j) {
    int seg = w * 4 + j;
    int r = seg * 8 + lhi;
    int gr = mt * 128 + r; if (gr >= ce) gr = ce - 1;
    abase[j] = (size_t)(off + gr) * HH + (size_t)((llo ^ (r & 7)) * 8);
    aoff[j] = seg * 512 + l * 8;
  }
  // B staging
  const int n0 = nt * 64;
  const float* srcD = bdown + (size_t)e * HH * DD + n0 + 4 * (tid & 15);
  int q2s[2], bw[2][4];
  #pragma unroll
  for (int s = 0; s < 2; ++s) {
    int idx = s * 256 + tid;
    int q2 = idx >> 4;
    q2s[s] = q2;
    #pragma unroll
    for (int i = 0; i < 4; ++i) bw[s][i] = (4 * (tid & 15) + i) * BW35 + q2;
  }
  const int wm = (w >> 1) * 64, wn = (w & 1) * 32;
  const int lr = l & 15, kg = l >> 4;
  const f32x4 zero = {0.f, 0.f, 0.f, 0.f};
  f32x4 acc[4][2];
  #pragma unroll
  for (int a = 0; a < 4; ++a)
    #pragma unroll
    for (int b = 0; b < 2; ++b) acc[a][b] = zero;

  float4 rd0[2], rd1[2];
  auto loadB = [&](int kt) {
    #pragma unroll
    for (int s = 0; s < 2; ++s) {
      const float* pD = srcD + (size_t)(kt * 64 + 2 * q2s[s]) * DD;
      rd0[s] = *reinterpret_cast<const float4*>(pD);
      rd1[s] = *reinterpret_cast<const float4*>(pD + DD);
    }
  };
  auto writeB = [&](int buf) {
    #pragma unroll
    for (int s = 0; s < 2; ++s) {
      const float* d0 = reinterpret_cast<const float*>(&rd0[s]);
      const float* d1 = reinterpret_cast<const float*>(&rd1[s]);
      #pragma unroll
      for (int i = 0; i < 4; ++i) Bu[buf][bw[s][i]] = packbf(d0[i], d1[i]);
    }
  };

  loadB(0);
  #pragma unroll
  for (int j = 0; j < 4; ++j) gl_lds16(hid + abase[j], &As[0][0][0] + aoff[j]);
  writeB(0);
  __syncthreads();
  int buf = 0;
  for (int kt = 0; kt < HH / 64; ++kt) {
    const bool more = (kt + 1) < HH / 64;
    if (more) {
      #pragma unroll
      for (int j = 0; j < 4; ++j)
        gl_lds16(hid + abase[j] + (kt + 1) * 64, &As[buf ^ 1][0][0] + aoff[j]);
      loadB(kt + 1);
    }
    #pragma unroll
    for (int ks = 0; ks < 2; ++ks) {
      bf16x8 av[4];
      #pragma unroll
      for (int fm = 0; fm < 4; ++fm) {
        int row = wm + fm * 16 + lr;
        int c = (ks * 4 + kg) ^ (row & 7);
        av[fm] = *reinterpret_cast<const bf16x8*>(&As[buf][row][c * 8]);
      }
      U4 t[2];
      #pragma unroll
      for (int fn = 0; fn < 2; ++fn) {
        const int nb = (wn + fn * 16 + lr) * BW35 + ks * 16 + kg * 4;
        #pragma unroll
        for (int j2 = 0; j2 < 4; ++j2) t[fn].u[j2] = Bu[buf][nb + j2];
      }
      #pragma unroll
      for (int fm = 0; fm < 4; ++fm)
        #pragma unroll
        for (int fn = 0; fn < 2; ++fn)
          acc[fm][fn] = __builtin_amdgcn_mfma_f32_16x16x32_bf16(av[fm], t[fn].v, acc[fm][fn], 0, 0, 0);
    }
    if (more) writeB(buf ^ 1);
    __syncthreads();
    buf ^= 1;
  }
  #pragma unroll
  for (int fn = 0; fn < 2; ++fn) {
    const int ng = n0 + wn + fn * 16 + lr;
    #pragma unroll
    for (int fm = 0; fm < 4; ++fm) {
      #pragma unroll
      for (int jj = 0; jj < 4; ++jj) {
        int m = mt * 128 + wm + fm * 16 + kg * 4 + jj;
        if (m < ce)
          op[(size_t)(off + m) * DD + ng] = f2bf(acc[fm][fn][jj]);
      }
    }
  }
}

// ---------------- combine + RMSNorm ----------------
__global__ __launch_bounds__(256) void k_norm(
    const unsigned short* __restrict__ op, const int* __restrict__ woff,
    const int* __restrict__ rec, const float* __restrict__ wrec,
    const float* __restrict__ nw, float* __restrict__ out) {
  const int t = blockIdx.x;
  const int tid = threadIdx.x;
  __shared__ float red[4];
  const int e1 = rec[t * 4 + 0], p1 = rec[t * 4 + 1];
  const int e2 = rec[t * 4 + 2], p2 = rec[t * 4 + 3];
  const float w1 = wrec[t * 2 + 0], w2 = wrec[t * 2 + 1];
  const unsigned short* pa = op + (size_t)(woff[e1] + p1) * DD;
  const unsigned short* pb = op + (size_t)(woff[e2] + p2) * DD;
  float v[4]; float ss = 0.f;
  #pragma unroll
  for (int q = 0; q < 4; ++q) {
    int i = q * 256 + tid;
    v[q] = w1 * bf2f(pa[i]) + w2 * bf2f(pb[i]);
    ss += v[q] * v[q];
  }
  #pragma unroll
  for (int o = 32; o > 0; o >>= 1) ss += __shfl_xor(ss, o);
  if ((tid & 63) == 0) red[tid >> 6] = ss;
  __syncthreads();
  const float tot = red[0] + red[1] + red[2] + red[3];
  const float scl = rsqrtf(tot * (1.f / DD) + 1e-6f);
  #pragma unroll
  for (int q = 0; q < 4; ++q) {
    int i = q * 256 + tid;
    out[(size_t)t * DD + i] = v[q] * scl * nw[i];
  }
}

extern "C" void kernel_launch(void* const* d_in, const int* in_sizes, int n_in,
                              void* d_out, int out_size, void* d_ws, size_t ws_size,
                              hipStream_t stream) {
  const float* x      = (const float*)d_in[0];
  const float* rw     = (const float*)d_in[1];
  const float* rb     = (const float*)d_in[2];
  const float* bmag   = (const float*)d_in[3];
  const float* bfreq  = (const float*)d_in[4];
  const float* bphase = (const float*)d_in[5];
  const float* bdown  = (const float*)d_in[6];
  const float* nw     = (const float*)d_in[7];
  float* out = (float*)d_out;
  char* ws = (char*)d_ws;
  const size_t MB = 1024 * 1024;
  int*   cnt    = (int*)(ws + 0);          // 16 int
  int*   work1  = (int*)(ws + 128);        // WM128*2 int
  int*   woff   = (int*)(ws + 2048);       // 16 int
  int*   list   = (int*)(ws + 4096);       // 16*2048 int
  int*   rec    = (int*)(ws + 139264);     // 2048*4 int
  float* wrec   = (float*)(ws + 172032);   // 2048*2 f32
  unsigned short* xbf = (unsigned short*)(ws + 1 * MB);    // 4 MB
  unsigned short* hid = (unsigned short*)(ws + 5 * MB);    // 16 MB
  unsigned short* op  = (unsigned short*)(ws + 21 * MB);   // 8 MB

  hipMemsetAsync(cnt, 0, 64, stream);
  k_router<<<TT, 256, 0, stream>>>(x, rw, rb, cnt, list, rec, wrec, xbf);
  k_sched<<<1, 64, 0, stream>>>(cnt, work1, woff);
  k_up<<<dim3(WM128, HH / 64), 256, 0, stream>>>(xbf, bmag, bfreq, bphase,
                                                 cnt, list, work1, woff, hid);
  k_down<<<dim3(WM128, DD / 64), 256, 0, stream>>>(hid, bdown, cnt, work1, woff, op);
  k_norm<<<TT, 256, 0, stream>>>(op, woff, rec, wrec, nw, out);
}

// Round 11
// 289.935 us; speedup vs baseline: 1.1584x; 1.0165x over previous
//
#include <hip/hip_runtime.h>
#include <hip/hip_bf16.h>
#include <cstdint>
#include <cstddef>

#define TT 2048      // tokens (b*t)
#define DD 1024      // d
#define HH 2048      // h
#define NE 16        // experts
#define WM128 48     // max (expert, 128-row block) work items
#define BW35 35      // B-tile row stride in u32 (64 rows x 35): 2-way-free banks both sides

typedef __bf16 bf16x8 __attribute__((ext_vector_type(8)));
typedef float f32x4 __attribute__((ext_vector_type(4)));

__device__ __forceinline__ unsigned short f2bf(float f) {
  union { float f; unsigned u; } v; v.f = f;
  unsigned r = (v.u + 0x7FFFu + ((v.u >> 16) & 1u)) >> 16;  // RNE
  return (unsigned short)r;
}
__device__ __forceinline__ float bf2f(unsigned short s) {
  union { unsigned u; float f; } v; v.u = ((unsigned)s) << 16;
  return v.f;
}
__device__ __forceinline__ unsigned packbf(float lo, float hi) {
  return (unsigned)f2bf(lo) | ((unsigned)f2bf(hi) << 16);
}

__device__ __forceinline__ void gl_lds16(const void* g, void* l) {
  __builtin_amdgcn_global_load_lds(
      (const __attribute__((address_space(1))) unsigned int*)g,
      (__attribute__((address_space(3))) unsigned int*)l, 16, 0, 0);
}

union U4 { unsigned int u[4]; bf16x8 v; };

// Counted-vmcnt barrier: certify own gl_lds landed (N newer B-loads may fly),
// LDS writes visible, then raw s_barrier (no vmcnt(0) drain).
#define BARRIER_N(N)                                            \
  do {                                                          \
    asm volatile("s_waitcnt vmcnt(" #N ")" ::: "memory");       \
    asm volatile("s_waitcnt lgkmcnt(0)" ::: "memory");          \
    __builtin_amdgcn_sched_barrier(0);                          \
    __builtin_amdgcn_s_barrier();                               \
    __builtin_amdgcn_sched_barrier(0);                          \
  } while (0)

// ---------------- router + top-2 + bucketing + x cvt (fused) ----------------
__global__ __launch_bounds__(256) void k_router(
    const float* __restrict__ x, const float* __restrict__ rw,
    const float* __restrict__ rb, int* __restrict__ cnt,
    int* __restrict__ list_tok, int* __restrict__ rec,
    float* __restrict__ wrec, unsigned short* __restrict__ xbf) {
  const int t = blockIdx.x;
  __shared__ float xs[DD];
  __shared__ float part[256];
  __shared__ float sc[NE];
  const float* xr = x + (size_t)t * DD;
  for (int i = threadIdx.x; i < DD; i += 256) xs[i] = xr[i];
  __syncthreads();
  {
    int i = threadIdx.x * 4;
    ushort4 o = { f2bf(xs[i]), f2bf(xs[i + 1]), f2bf(xs[i + 2]), f2bf(xs[i + 3]) };
    *reinterpret_cast<ushort4*>(xbf + (size_t)t * DD + i) = o;
  }
  const int e = threadIdx.x >> 4, j = threadIdx.x & 15;
  const float* w = rw + (size_t)e * DD;
  float s = 0.f;
  for (int i = j; i < DD; i += 16) s += xs[i] * w[i];
  part[threadIdx.x] = s;
  __syncthreads();
  if (threadIdx.x < NE) {
    float v = rb[threadIdx.x];
    #pragma unroll
    for (int q = 0; q < 16; ++q) v += part[threadIdx.x * 16 + q];
    sc[threadIdx.x] = v;
  }
  __syncthreads();
  if (threadIdx.x == 0) {
    int e1 = 0; float v1 = sc[0];
    #pragma unroll
    for (int q = 1; q < NE; ++q) { if (sc[q] > v1) { v1 = sc[q]; e1 = q; } }
    int e2 = -1; float v2 = -3.4e38f;
    #pragma unroll
    for (int q = 0; q < NE; ++q) {
      if (q != e1 && sc[q] > v2) { v2 = sc[q]; e2 = q; }
    }
    float ex = expf(v2 - v1);
    float w1 = 1.f / (1.f + ex);
    float w2 = ex / (1.f + ex);
    int p1 = atomicAdd(&cnt[e1], 1);
    int p2 = atomicAdd(&cnt[e2], 1);
    list_tok[e1 * TT + p1] = t;
    list_tok[e2 * TT + p2] = t;
    rec[t * 4 + 0] = e1; rec[t * 4 + 1] = p1;
    rec[t * 4 + 2] = e2; rec[t * 4 + 3] = p2;
    wrec[t * 2 + 0] = w1; wrec[t * 2 + 1] = w2;
  }
}

// ---------------- work-table builder ----------------
__global__ void k_sched(const int* __restrict__ cnt, int* __restrict__ work128,
                        int* __restrict__ woff) {
  if (threadIdx.x == 0) {
    int o = 0, n1 = 0;
    for (int e = 0; e < NE; ++e) {
      int ce = cnt[e];
      int a = (ce + 127) >> 7;
      for (int mb = 0; mb < a; ++mb) { work128[n1 * 2] = e; work128[n1 * 2 + 1] = mb; ++n1; }
      woff[e] = o; o += ce;
    }
    for (int q = n1; q < WM128; ++q) { work128[q * 2] = -1; work128[q * 2 + 1] = 0; }
  }
}

// ---------------- up GEMMs (mag,freq) + activation ----------------
// R10 layout; counted-vmcnt barriers + 2-deep B prefetch (sets A/B).
__global__ __launch_bounds__(256, 2) void k_up(
    const unsigned short* __restrict__ xbf,
    const float* __restrict__ bmag,    // [e][DD][HH]
    const float* __restrict__ bfreq,   // [e][DD][HH]
    const float* __restrict__ bphase,
    const int* __restrict__ cnt, const int* __restrict__ list_tok,
    const int* __restrict__ work, const int* __restrict__ woff,
    unsigned short* __restrict__ hid) {
  const int e = work[blockIdx.x * 2 + 0];
  if (e < 0) return;
  const int mt = work[blockIdx.x * 2 + 1];
  const int nt = blockIdx.y;
  const int ce = cnt[e];
  const int off = woff[e];
  __shared__ unsigned short As[2][128][64];    // 32 KB
  __shared__ unsigned int BuM[2][64 * BW35];   // 17.5 KB
  __shared__ unsigned int BuF[2][64 * BW35];   // 17.5 KB
  __shared__ int toks[128];
  const int tid = threadIdx.x;
  if (tid < 128) {
    int r = mt * 128 + tid;
    toks[tid] = list_tok[e * TT + (r < ce ? r : ce - 1)];
  }
  __syncthreads();
  const int w = tid >> 6, l = tid & 63;
  const int lhi = l >> 3, llo = l & 7;
  size_t abase[4]; int aoff[4];
  #pragma unroll
  for (int j = 0; j < 4; ++j) {
    int seg = w * 4 + j;
    int r = seg * 8 + lhi;
    abase[j] = (size_t)toks[r] * DD + (size_t)((llo ^ (r & 7)) * 8);
    aoff[j] = seg * 512 + l * 8;
  }
  const int n0 = nt * 64;
  const float* srcM = bmag  + (size_t)e * DD * HH + n0 + 4 * (tid & 15);
  const float* srcF = bfreq + (size_t)e * DD * HH + n0 + 4 * (tid & 15);
  int q2s[2], bwv[2][4];
  #pragma unroll
  for (int s = 0; s < 2; ++s) {
    int idx = s * 256 + tid;
    int q2 = idx >> 4;
    q2s[s] = q2;
    #pragma unroll
    for (int i = 0; i < 4; ++i) bwv[s][i] = (4 * (tid & 15) + i) * BW35 + q2;
  }
  const int wm = (w >> 1) * 64, wn = (w & 1) * 32;
  const int lr = l & 15, kg = l >> 4;
  const f32x4 zero = {0.f, 0.f, 0.f, 0.f};
  f32x4 accM[4][2], accF[4][2];
  #pragma unroll
  for (int a = 0; a < 4; ++a)
    #pragma unroll
    for (int b = 0; b < 2; ++b) { accM[a][b] = zero; accF[a][b] = zero; }

  // Two named B register sets (rule #20: static names, no runtime indexing)
  float4 Am0[2], Am1[2], Af0[2], Af1[2];   // set A
  float4 Bm0[2], Bm1[2], Bf0[2], Bf1[2];   // set B

  auto glA = [&](int kt, int buf) {
    #pragma unroll
    for (int j = 0; j < 4; ++j)
      gl_lds16(xbf + abase[j] + kt * 64, &As[buf][0][0] + aoff[j]);
  };
  auto loadBA = [&](int kt) {
    #pragma unroll
    for (int s = 0; s < 2; ++s) {
      const float* pM = srcM + (size_t)(kt * 64 + 2 * q2s[s]) * HH;
      const float* pF = srcF + (size_t)(kt * 64 + 2 * q2s[s]) * HH;
      Am0[s] = *reinterpret_cast<const float4*>(pM);
      Am1[s] = *reinterpret_cast<const float4*>(pM + HH);
      Af0[s] = *reinterpret_cast<const float4*>(pF);
      Af1[s] = *reinterpret_cast<const float4*>(pF + HH);
    }
  };
  auto loadBB = [&](int kt) {
    #pragma unroll
    for (int s = 0; s < 2; ++s) {
      const float* pM = srcM + (size_t)(kt * 64 + 2 * q2s[s]) * HH;
      const float* pF = srcF + (size_t)(kt * 64 + 2 * q2s[s]) * HH;
      Bm0[s] = *reinterpret_cast<const float4*>(pM);
      Bm1[s] = *reinterpret_cast<const float4*>(pM + HH);
      Bf0[s] = *reinterpret_cast<const float4*>(pF);
      Bf1[s] = *reinterpret_cast<const float4*>(pF + HH);
    }
  };
  auto writeBA = [&](int buf) {
    #pragma unroll
    for (int s = 0; s < 2; ++s) {
      const float* m0 = reinterpret_cast<const float*>(&Am0[s]);
      const float* m1 = reinterpret_cast<const float*>(&Am1[s]);
      const float* f0 = reinterpret_cast<const float*>(&Af0[s]);
      const float* f1 = reinterpret_cast<const float*>(&Af1[s]);
      #pragma unroll
      for (int i = 0; i < 4; ++i) {
        BuM[buf][bwv[s][i]] = packbf(m0[i], m1[i]);
        BuF[buf][bwv[s][i]] = packbf(f0[i], f1[i]);
      }
    }
  };
  auto writeBB = [&](int buf) {
    #pragma unroll
    for (int s = 0; s < 2; ++s) {
      const float* m0 = reinterpret_cast<const float*>(&Bm0[s]);
      const float* m1 = reinterpret_cast<const float*>(&Bm1[s]);
      const float* f0 = reinterpret_cast<const float*>(&Bf0[s]);
      const float* f1 = reinterpret_cast<const float*>(&Bf1[s]);
      #pragma unroll
      for (int i = 0; i < 4; ++i) {
        BuM[buf][bwv[s][i]] = packbf(m0[i], m1[i]);
        BuF[buf][bwv[s][i]] = packbf(f0[i], f1[i]);
      }
    }
  };
  auto compute = [&](int buf) {
    #pragma unroll
    for (int ks = 0; ks < 2; ++ks) {
      bf16x8 av[4];
      #pragma unroll
      for (int fm = 0; fm < 4; ++fm) {
        int row = wm + fm * 16 + lr;
        int c = (ks * 4 + kg) ^ (row & 7);
        av[fm] = *reinterpret_cast<const bf16x8*>(&As[buf][row][c * 8]);
      }
      U4 tm[2], tf[2];
      #pragma unroll
      for (int fn = 0; fn < 2; ++fn) {
        const int nb = (wn + fn * 16 + lr) * BW35 + ks * 16 + kg * 4;
        #pragma unroll
        for (int j2 = 0; j2 < 4; ++j2) {
          tm[fn].u[j2] = BuM[buf][nb + j2];
          tf[fn].u[j2] = BuF[buf][nb + j2];
        }
      }
      #pragma unroll
      for (int fm = 0; fm < 4; ++fm)
        #pragma unroll
        for (int fn = 0; fn < 2; ++fn) {
          accM[fm][fn] = __builtin_amdgcn_mfma_f32_16x16x32_bf16(av[fm], tm[fn].v, accM[fm][fn], 0, 0, 0);
          accF[fm][fn] = __builtin_amdgcn_mfma_f32_16x16x32_bf16(av[fm], tf[fn].v, accF[fm][fn], 0, 0, 0);
        }
    }
  };

  // prologue: glA first (oldest VMEM), then B sets for kt=0,1
  glA(0, 0);
  __builtin_amdgcn_sched_barrier(0);
  loadBA(0);
  loadBB(1);
  writeBA(0);            // auto-waits set A (and glA, older)
  BARRIER_N(8);
  // phases kt=0..15, unrolled x2: even computes buf0, odd buf1
  for (int kt = 0; kt < 16; kt += 2) {
    // even phase
    glA(kt + 1, 1);
    __builtin_amdgcn_sched_barrier(0);
    loadBA(kt + 2 < 16 ? kt + 2 : 15);
    compute(0);
    writeBB(1);
    BARRIER_N(8);
    // odd phase
    const bool more = kt + 2 < 16;
    if (more) {
      glA(kt + 2, 0);
      __builtin_amdgcn_sched_barrier(0);
      loadBB(kt + 3 < 16 ? kt + 3 : 15);
    }
    compute(1);
    if (more) {
      writeBA(0);
      BARRIER_N(8);
    }
  }
  // epilogue: activation + store
  #pragma unroll
  for (int fn = 0; fn < 2; ++fn) {
    const int ng = n0 + wn + fn * 16 + lr;
    const float ph = bphase[e * HH + ng] + 0.1f;
    #pragma unroll
    for (int fm = 0; fm < 4; ++fm) {
      #pragma unroll
      for (int jj = 0; jj < 4; ++jj) {
        int m = mt * 128 + wm + fm * 16 + kg * 4 + jj;
        if (m < ce) {
          float mv = accM[fm][fn][jj];
          float fv = accF[fm][fn][jj];
          float exn = __expf(-fabsf(fv));
          float sp = fmaxf(fv, 0.f) + __logf(1.f + exn);   // stable softplus
          float t2 = __expf(2.f * mv);
          float th = 1.f - 2.f / (t2 + 1.f);               // tanh
          float hv = th * __cosf(sp + ph);
          hid[(size_t)(off + m) * HH + ng] = f2bf(hv);
        }
      }
    }
  }
}

// ---------------- down GEMM ----------------
__global__ __launch_bounds__(256, 3) void k_down(
    const unsigned short* __restrict__ hid,
    const float* __restrict__ bdown,   // [e][HH][DD]
    const int* __restrict__ cnt,
    const int* __restrict__ work, const int* __restrict__ woff,
    unsigned short* __restrict__ op) {
  const int e = work[blockIdx.x * 2 + 0];
  if (e < 0) return;
  const int mt = work[blockIdx.x * 2 + 1];
  const int nt = blockIdx.y;
  const int ce = cnt[e];
  const int off = woff[e];
  __shared__ unsigned short As[2][128][64];    // 32 KB
  __shared__ unsigned int Bu[2][64 * BW35];    // 17.5 KB
  const int tid = threadIdx.x;
  const int w = tid >> 6, l = tid & 63;
  const int lhi = l >> 3, llo = l & 7;
  size_t abase[4]; int aoff[4];
  #pragma unroll
  for (int j = 0; j < 4; ++j) {
    int seg = w * 4 + j;
    int r = seg * 8 + lhi;
    int gr = mt * 128 + r; if (gr >= ce) gr = ce - 1;
    abase[j] = (size_t)(off + gr) * HH + (size_t)((llo ^ (r & 7)) * 8);
    aoff[j] = seg * 512 + l * 8;
  }
  const int n0 = nt * 64;
  const float* srcD = bdown + (size_t)e * HH * DD + n0 + 4 * (tid & 15);
  int q2s[2], bwv[2][4];
  #pragma unroll
  for (int s = 0; s < 2; ++s) {
    int idx = s * 256 + tid;
    int q2 = idx >> 4;
    q2s[s] = q2;
    #pragma unroll
    for (int i = 0; i < 4; ++i) bwv[s][i] = (4 * (tid & 15) + i) * BW35 + q2;
  }
  const int wm = (w >> 1) * 64, wn = (w & 1) * 32;
  const int lr = l & 15, kg = l >> 4;
  const f32x4 zero = {0.f, 0.f, 0.f, 0.f};
  f32x4 acc[4][2];
  #pragma unroll
  for (int a = 0; a < 4; ++a)
    #pragma unroll
    for (int b = 0; b < 2; ++b) acc[a][b] = zero;

  float4 Ad0[2], Ad1[2];   // set A
  float4 Bd0[2], Bd1[2];   // set B

  auto glA = [&](int kt, int buf) {
    #pragma unroll
    for (int j = 0; j < 4; ++j)
      gl_lds16(hid + abase[j] + kt * 64, &As[buf][0][0] + aoff[j]);
  };
  auto loadBA = [&](int kt) {
    #pragma unroll
    for (int s = 0; s < 2; ++s) {
      const float* pD = srcD + (size_t)(kt * 64 + 2 * q2s[s]) * DD;
      Ad0[s] = *reinterpret_cast<const float4*>(pD);
      Ad1[s] = *reinterpret_cast<const float4*>(pD + DD);
    }
  };
  auto loadBB = [&](int kt) {
    #pragma unroll
    for (int s = 0; s < 2; ++s) {
      const float* pD = srcD + (size_t)(kt * 64 + 2 * q2s[s]) * DD;
      Bd0[s] = *reinterpret_cast<const float4*>(pD);
      Bd1[s] = *reinterpret_cast<const float4*>(pD + DD);
    }
  };
  auto writeBA = [&](int buf) {
    #pragma unroll
    for (int s = 0; s < 2; ++s) {
      const float* d0 = reinterpret_cast<const float*>(&Ad0[s]);
      const float* d1 = reinterpret_cast<const float*>(&Ad1[s]);
      #pragma unroll
      for (int i = 0; i < 4; ++i) Bu[buf][bwv[s][i]] = packbf(d0[i], d1[i]);
    }
  };
  auto writeBB = [&](int buf) {
    #pragma unroll
    for (int s = 0; s < 2; ++s) {
      const float* d0 = reinterpret_cast<const float*>(&Bd0[s]);
      const float* d1 = reinterpret_cast<const float*>(&Bd1[s]);
      #pragma unroll
      for (int i = 0; i < 4; ++i) Bu[buf][bwv[s][i]] = packbf(d0[i], d1[i]);
    }
  };
  auto compute = [&](int buf) {
    #pragma unroll
    for (int ks = 0; ks < 2; ++ks) {
      bf16x8 av[4];
      #pragma unroll
      for (int fm = 0; fm < 4; ++fm) {
        int row = wm + fm * 16 + lr;
        int c = (ks * 4 + kg) ^ (row & 7);
        av[fm] = *reinterpret_cast<const bf16x8*>(&As[buf][row][c * 8]);
      }
      U4 t[2];
      #pragma unroll
      for (int fn = 0; fn < 2; ++fn) {
        const int nb = (wn + fn * 16 + lr) * BW35 + ks * 16 + kg * 4;
        #pragma unroll
        for (int j2 = 0; j2 < 4; ++j2) t[fn].u[j2] = Bu[buf][nb + j2];
      }
      #pragma unroll
      for (int fm = 0; fm < 4; ++fm)
        #pragma unroll
        for (int fn = 0; fn < 2; ++fn)
          acc[fm][fn] = __builtin_amdgcn_mfma_f32_16x16x32_bf16(av[fm], t[fn].v, acc[fm][fn], 0, 0, 0);
    }
  };

  glA(0, 0);
  __builtin_amdgcn_sched_barrier(0);
  loadBA(0);
  loadBB(1);
  writeBA(0);
  BARRIER_N(4);
  for (int kt = 0; kt < 32; kt += 2) {
    glA(kt + 1, 1);
    __builtin_amdgcn_sched_barrier(0);
    loadBA(kt + 2 < 32 ? kt + 2 : 31);
    compute(0);
    writeBB(1);
    BARRIER_N(4);
    const bool more = kt + 2 < 32;
    if (more) {
      glA(kt + 2, 0);
      __builtin_amdgcn_sched_barrier(0);
      loadBB(kt + 3 < 32 ? kt + 3 : 31);
    }
    compute(1);
    if (more) {
      writeBA(0);
      BARRIER_N(4);
    }
  }
  #pragma unroll
  for (int fn = 0; fn < 2; ++fn) {
    const int ng = n0 + wn + fn * 16 + lr;
    #pragma unroll
    for (int fm = 0; fm < 4; ++fm) {
      #pragma unroll
      for (int jj = 0; jj < 4; ++jj) {
        int m = mt * 128 + wm + fm * 16 + kg * 4 + jj;
        if (m < ce)
          op[(size_t)(off + m) * DD + ng] = f2bf(acc[fm][fn][jj]);
      }
    }
  }
}

// ---------------- combine + RMSNorm ----------------
__global__ __launch_bounds__(256) void k_norm(
    const unsigned short* __restrict__ op, const int* __restrict__ woff,
    const int* __restrict__ rec, const float* __restrict__ wrec,
    const float* __restrict__ nw, float* __restrict__ out) {
  const int t = blockIdx.x;
  const int tid = threadIdx.x;
  __shared__ float red[4];
  const int e1 = rec[t * 4 + 0], p1 = rec[t * 4 + 1];
  const int e2 = rec[t * 4 + 2], p2 = rec[t * 4 + 3];
  const float w1 = wrec[t * 2 + 0], w2 = wrec[t * 2 + 1];
  const unsigned short* pa = op + (size_t)(woff[e1] + p1) * DD;
  const unsigned short* pb = op + (size_t)(woff[e2] + p2) * DD;
  float v[4]; float ss = 0.f;
  #pragma unroll
  for (int q = 0; q < 4; ++q) {
    int i = q * 256 + tid;
    v[q] = w1 * bf2f(pa[i]) + w2 * bf2f(pb[i]);
    ss += v[q] * v[q];
  }
  #pragma unroll
  for (int o = 32; o > 0; o >>= 1) ss += __shfl_xor(ss, o);
  if ((tid & 63) == 0) red[tid >> 6] = ss;
  __syncthreads();
  const float tot = red[0] + red[1] + red[2] + red[3];
  const float scl = rsqrtf(tot * (1.f / DD) + 1e-6f);
  #pragma unroll
  for (int q = 0; q < 4; ++q) {
    int i = q * 256 + tid;
    out[(size_t)t * DD + i] = v[q] * scl * nw[i];
  }
}

extern "C" void kernel_launch(void* const* d_in, const int* in_sizes, int n_in,
                              void* d_out, int out_size, void* d_ws, size_t ws_size,
                              hipStream_t stream) {
  const float* x      = (const float*)d_in[0];
  const float* rw     = (const float*)d_in[1];
  const float* rb     = (const float*)d_in[2];
  const float* bmag   = (const float*)d_in[3];
  const float* bfreq  = (const float*)d_in[4];
  const float* bphase = (const float*)d_in[5];
  const float* bdown  = (const float*)d_in[6];
  const float* nw     = (const float*)d_in[7];
  float* out = (float*)d_out;
  char* ws = (char*)d_ws;
  const size_t MB = 1024 * 1024;
  int*   cnt    = (int*)(ws + 0);          // 16 int
  int*   work1  = (int*)(ws + 128);        // WM128*2 int
  int*   woff   = (int*)(ws + 2048);       // 16 int
  int*   list   = (int*)(ws + 4096);       // 16*2048 int
  int*   rec    = (int*)(ws + 139264);     // 2048*4 int
  float* wrec   = (float*)(ws + 172032);   // 2048*2 f32
  unsigned short* xbf = (unsigned short*)(ws + 1 * MB);    // 4 MB
  unsigned short* hid = (unsigned short*)(ws + 5 * MB);    // 16 MB
  unsigned short* op  = (unsigned short*)(ws + 21 * MB);   // 8 MB

  hipMemsetAsync(cnt, 0, 64, stream);
  k_router<<<TT, 256, 0, stream>>>(x, rw, rb, cnt, list, rec, wrec, xbf);
  k_sched<<<1, 64, 0, stream>>>(cnt, work1, woff);
  k_up<<<dim3(WM128, HH / 64), 256, 0, stream>>>(xbf, bmag, bfreq, bphase,
                                                 cnt, list, work1, woff, hid);
  k_down<<<dim3(WM128, DD / 64), 256, 0, stream>>>(hid, bdown, cnt, work1, woff, op);
  k_norm<<<TT, 256, 0, stream>>>(op, woff, rec, wrec, nw, out);
}